// Round 2
// baseline (1869.785 us; speedup 1.0000x reference)
//
#include <hip/hip_runtime.h>
#include <cfloat>
#include <cmath>

constexpr int NTILES = 79;   // ceil(10000 / 128) for the read matmul

// ---------------- workspace layout (float offsets) ----------------
enum : int {
  WS_XR    = 0,        // 16*512
  WS_UPDW  = 8192,     // 48
  WS_READW = 8240,     // 48
  WS_PMAX  = 8288,     // 3*16*79
  WS_PIDX  = 12080,    // 3*16*79 (ints)
  WS_RNEW  = 15872,    // 48*256
  WS_M     = 28160,    // 16*256
  WS_XC    = 32256,    // 48*768
  WS_TPA   = 69120,    // 2*4*16*512  phase-A logit partials
  WS_BAR   = 134656,   // grid barrier counter (1 uint)
  WS_XU    = 151040,   // 16*512  x*(fa_u output)
  WS_TPU   = 216576,   // 6*48*768
  WS_XU2   = 474624,   // 48*768  xc*(fa_um y+b2)
  WS_TPM   = 769536,   // 4*16*512
  WS_XA    = 810496,   // 16*512  xc*(fa_am y+b2)
};

struct Params {
  const float *x, *mem;
  const float *w1r, *b1r, *w2r, *b2r, *Wrd, *brd;
  const float *w1u, *b1u, *w2u, *b2u, *Wuw, *buw;
  const float *w1um, *b1um, *w2um, *b2um, *Wum, *bum;
  const float *w1am, *b1am, *w2am, *b2am, *Wam, *bam;
  float *XR, *XU, *UPDW, *RDW, *PMAX;
  int   *PIDX;
  float *RNEW, *M, *XC, *TPA, *TPU, *XU2, *TPM, *XA, *out;
};

// ---------------- reductions (wave = 64) ----------------
__device__ __forceinline__ float wave_sum(float v) {
#pragma unroll
  for (int o = 32; o > 0; o >>= 1) v += __shfl_xor(v, o);
  return v;
}
__device__ __forceinline__ float wave_max(float v) {
#pragma unroll
  for (int o = 32; o > 0; o >>= 1) v = fmaxf(v, __shfl_xor(v, o));
  return v;
}
__device__ __forceinline__ float block_sum(float v, float* red) {
  int lane = threadIdx.x & 63, w = threadIdx.x >> 6, nw = blockDim.x >> 6;
  v = wave_sum(v);
  __syncthreads();
  if (lane == 0) red[w] = v;
  __syncthreads();
  float s = 0.f;
  for (int k = 0; k < nw; k++) s += red[k];
  return s;
}

// ---------------- device-scope grid barrier ----------------
// Monotonic arrival counter; barrier k waits until bar >= k*gridDim.
// Release: __threadfence + agent-scope add.  Acquire: agent-scope load.
// Residency of all 256 blocks is GUARANTEED by hipLaunchCooperativeKernel.
__device__ __forceinline__ void grid_sync(unsigned* bar, unsigned target) {
  __syncthreads();               // drains this wave's mem ops pre-barrier
  if (threadIdx.x == 0) {
    __threadfence();             // device-scope release of this block's writes
    __hip_atomic_fetch_add(bar, 1u, __ATOMIC_RELEASE, __HIP_MEMORY_SCOPE_AGENT);
    while (__hip_atomic_load(bar, __ATOMIC_ACQUIRE, __HIP_MEMORY_SCOPE_AGENT) < target)
      __builtin_amdgcn_s_sleep(2);
  }
  __syncthreads();
}

// ---------------- mm core ----------------
// 512 thr = 8 waves; wave w -> rows (2w,2w+1); lane -> 2 consecutive cols.
__device__ __forceinline__ void mm_rows(const float* __restrict__ xs, int ldx, int K,
                                        const float* __restrict__ W, int ldw, int jbase,
                                        float2& ra, float2& rb) {
  int lane = threadIdx.x & 63, w = threadIdx.x >> 6;
  const float* xa = xs + (w * 2) * ldx;
  const float* xb = xa + ldx;
  const float* Wp = W + jbase + lane * 2;
  float a00 = 0.f, a01 = 0.f, a10 = 0.f, a11 = 0.f;
#pragma unroll 8
  for (int k = 0; k < K; k++) {
    float2 wv = *(const float2*)(Wp + (size_t)k * ldw);
    float xav = xa[k], xbv = xb[k];
    a00 = fmaf(xav, wv.x, a00); a01 = fmaf(xav, wv.y, a01);
    a10 = fmaf(xbv, wv.x, a10); a11 = fmaf(xbv, wv.y, a11);
  }
  ra = make_float2(a00, a01);
  rb = make_float2(a10, a11);
}
__device__ __forceinline__ void store_tile16(float* __restrict__ T, int ldt, int jbase,
                                             float2 ra, float2 rb) {
  int lane = threadIdx.x & 63, w = threadIdx.x >> 6;
  int r0 = w * 2, j0 = jbase + lane * 2;
  *(float2*)(T + (size_t)r0 * ldt + j0) = ra;
  *(float2*)(T + (size_t)(r0 + 1) * ldt + j0) = rb;
}

// Per-wave in-place softmax of rows 2w,2w+1 of a 16-row LDS tile (stride ncol).
// Safe without a following __syncthreads: mm_rows wave w reads only rows 2w,2w+1.
__device__ __forceinline__ void softmax_rows(float* xs, int ncol) {
  int lane = threadIdx.x & 63, w = threadIdx.x >> 6;
#pragma unroll
  for (int rr = 0; rr < 2; rr++) {
    float* row = xs + (size_t)(w * 2 + rr) * ncol;
    float mx = -FLT_MAX;
    for (int j = lane; j < ncol; j += 64) mx = fmaxf(mx, row[j]);
    mx = wave_max(mx);
    float acc = 0.f;
    for (int j = lane; j < ncol; j += 64) {
      float e = expf(row[j] - mx);
      row[j] = e;
      acc += e;
    }
    acc = wave_sum(acc);
    float inv = 1.f / acc;
    for (int j = lane; j < ncol; j += 64) row[j] *= inv;
  }
}

// ================= the mega-kernel =================
__global__ __launch_bounds__(512, 2) void mega(Params p, unsigned* bar) {
  __shared__ __align__(16) float xs[12288];   // 48 KB: 16x768 max tile
  __shared__ float red[16];
  __shared__ int sidx;
  const int bid = blockIdx.x, tid = threadIdx.x;
  const int lane = tid & 63, w = tid >> 6;
  unsigned ph = 0;
#define GSYNC() do { ++ph; grid_sync(bar, ph * 256u); } while (0)

  // ---- P1: fa_r/fa_u mm1 partials (K-split). 32 blocks. ----
  if (bid < 32) {
    int jt = bid & 3, ks = (bid >> 2) & 3, m = bid >> 4;
    for (int t = tid; t < 2048; t += 512) {
      int b = t >> 7, kk = t & 127;
      xs[t] = p.x[b * 512 + ks * 128 + kk];
    }
    __syncthreads();
    float2 ra, rb;
    mm_rows(xs, 128, 128, (m ? p.w1u : p.w1r) + (size_t)(ks * 128) * 512, 512, jt * 128, ra, rb);
    store_tile16(p.TPA + (size_t)((m * 4 + ks) * 16) * 512, 512, jt * 128, ra, rb);
  }
  GSYNC();

  // ---- P2: assemble logits + softmax (in-block) + mm2 + elementwise. 8 blocks. ----
  if (bid < 8) {
    int m = bid >> 2, jt = bid & 3;
    const float* b1 = m ? p.b1u : p.b1r;
    for (int e = tid; e < 8192; e += 512) {
      int b = e >> 9, j = e & 511;
      float v = b1[j];
#pragma unroll
      for (int ks = 0; ks < 4; ks++) v += p.TPA[(size_t)((m * 4 + ks) * 16 + b) * 512 + j];
      xs[e] = v;
    }
    __syncthreads();
    softmax_rows(xs, 512);
    float2 ra, rb;
    mm_rows(xs, 512, 512, m ? p.w2u : p.w2r, 512, jt * 128, ra, rb);
    int r0 = w * 2, j0 = jt * 128 + lane * 2;
    const float* b2 = m ? p.b2u : p.b2r;
    float b20 = b2[j0], b21 = b2[j0 + 1];
    float* dst = m ? p.XU : p.XR;
    float2 x0 = *(const float2*)(p.x + r0 * 512 + j0);
    float2 x1 = *(const float2*)(p.x + (r0 + 1) * 512 + j0);
    *(float2*)(dst + r0 * 512 + j0)       = make_float2(x0.x * (ra.x + b20), x0.y * (ra.y + b21));
    *(float2*)(dst + (r0 + 1) * 512 + j0) = make_float2(x1.x * (rb.x + b20), x1.y * (rb.y + b21));
  }
  GSYNC();

  // ---- P3: read matmul (blocks 0..236)  ||  UPDW sigmoid + M-zero (blocks 240..255) ----
  if (bid < 237) {
    int ii = bid / NTILES, tile = bid % NTILES;
    {
      const float4* s4 = (const float4*)p.XR;
      float4* d4 = (float4*)xs;
      for (int t = tid; t < 2048; t += 512) d4[t] = s4[t];
    }
    __syncthreads();
    int b0 = w * 2, b1 = b0 + 1;
    int s0 = tile * 128 + lane * 2;
    int sC = (s0 > 9998) ? 9998 : s0;
    const float* Wp = p.Wrd + ii * 10000 + sC;
    const float* xap = xs + b0 * 512;
    const float* xbp = xs + b1 * 512;
    float a00 = 0.f, a01 = 0.f, a10 = 0.f, a11 = 0.f;
#pragma unroll 8
    for (int c = 0; c < 512; c += 4) {
      float4 xa = *(const float4*)(xap + c);
      float4 xb = *(const float4*)(xbp + c);
      float2 w0 = *(const float2*)(Wp + (size_t)(c + 0) * 30000);
      float2 w1 = *(const float2*)(Wp + (size_t)(c + 1) * 30000);
      float2 w2 = *(const float2*)(Wp + (size_t)(c + 2) * 30000);
      float2 w3 = *(const float2*)(Wp + (size_t)(c + 3) * 30000);
      a00 = fmaf(xa.x, w0.x, a00); a01 = fmaf(xa.x, w0.y, a01);
      a10 = fmaf(xb.x, w0.x, a10); a11 = fmaf(xb.x, w0.y, a11);
      a00 = fmaf(xa.y, w1.x, a00); a01 = fmaf(xa.y, w1.y, a01);
      a10 = fmaf(xb.y, w1.x, a10); a11 = fmaf(xb.y, w1.y, a11);
      a00 = fmaf(xa.z, w2.x, a00); a01 = fmaf(xa.z, w2.y, a01);
      a10 = fmaf(xb.z, w2.x, a10); a11 = fmaf(xb.z, w2.y, a11);
      a00 = fmaf(xa.w, w3.x, a00); a01 = fmaf(xa.w, w3.y, a01);
      a10 = fmaf(xb.w, w3.x, a10); a11 = fmaf(xb.w, w3.y, a11);
    }
    float2 bb = *(const float2*)(p.brd + ii * 10000 + sC);
    bool ok0 = (s0 < 10000), ok1 = (s0 + 1 < 10000);
    float v00 = a00 + bb.x, v01 = a01 + bb.y;
    float v10 = a10 + bb.x, v11 = a11 + bb.y;
    float bv0 = ok0 ? v00 : -FLT_MAX; int bi0 = s0;
    if (ok1 && v01 > bv0) { bv0 = v01; bi0 = s0 + 1; }
    float bv1 = ok0 ? v10 : -FLT_MAX; int bi1 = s0;
    if (ok1 && v11 > bv1) { bv1 = v11; bi1 = s0 + 1; }
#pragma unroll
    for (int o = 32; o > 0; o >>= 1) {
      float ov = __shfl_down(bv0, o); int oi = __shfl_down(bi0, o);
      if (ov > bv0) { bv0 = ov; bi0 = oi; }
      ov = __shfl_down(bv1, o); oi = __shfl_down(bi1, o);
      if (ov > bv1) { bv1 = ov; bi1 = oi; }
    }
    if (lane == 0) {
      int base = (ii * 16 + b0) * NTILES + tile;
      p.PMAX[base] = bv0; p.PIDX[base] = bi0;
      base = (ii * 16 + b1) * NTILES + tile;
      p.PMAX[base] = bv1; p.PIDX[base] = bi1;
    }
  } else if (bid >= 240) {
    int b = bid - 240;
    float xu = p.XU[b * 512 + tid];
    if (tid < 256) p.M[b * 256 + tid] = 0.f;
    for (int i2 = 0; i2 < 3; i2++) {
      float si = block_sum(xu * p.Wuw[tid * 3 + i2], red);
      if (tid == 0) p.UPDW[b * 3 + i2] = 1.f / (1.f + expf(-(si + p.buw[i2])));
    }
  }
  GSYNC();

  // ---- P4: argmax finalize + gather XC = [mem_row, x]. 48 blocks. ----
  if (bid < 48) {
    int b = bid / 3, ii = bid % 3;
    if (tid < 64) {
      float bv = -FLT_MAX; int bix = 0;
      const float* pm = p.PMAX + (ii * 16 + b) * NTILES;
      const int* pi = p.PIDX + (ii * 16 + b) * NTILES;
      for (int t = tid; t < NTILES; t += 64) {
        float v = pm[t]; int ix = pi[t];
        if (v > bv || (v == bv && ix < bix)) { bv = v; bix = ix; }
      }
#pragma unroll
      for (int o = 32; o > 0; o >>= 1) {
        float ov = __shfl_down(bv, o); int oi = __shfl_down(bix, o);
        if (ov > bv || (ov == bv && oi < bix)) { bv = ov; bix = oi; }
      }
      if (tid == 0) { sidx = bix; p.RDW[bid] = tanhf(bv); }
    }
    __syncthreads();
    for (int t = tid; t < 768; t += 512)
      p.XC[(size_t)bid * 768 + t] = (t < 256)
          ? p.mem[((size_t)b * 10000 + sidx) * 256 + t]
          : p.x[b * 512 + (t - 256)];
  }
  GSYNC();

  // ---- P5: fa_um mm1 partials (K-split). 108 blocks. ----
  if (bid < 108) {
    int jt = bid % 6, ks = (bid / 6) % 6, g = bid / 36;
    for (int t = tid; t < 2048; t += 512) {
      int r = t >> 7, kk = t & 127;
      xs[t] = p.XC[(size_t)(g * 16 + r) * 768 + ks * 128 + kk];
    }
    __syncthreads();
    float2 ra, rb;
    mm_rows(xs, 128, 128, p.w1um + (size_t)(ks * 128) * 768, 768, jt * 128, ra, rb);
    store_tile16(p.TPU + (size_t)(ks * 48 + g * 16) * 768, 768, jt * 128, ra, rb);
  }
  GSYNC();

  // ---- P6: fa_um softmax + mm2 + elementwise (XU2 = xc*(y+b2um)). 18 blocks. ----
  if (bid < 18) {
    int g = bid / 6, jt = bid % 6;
    for (int e = tid; e < 12288; e += 512) {
      int r = e / 768, j = e - r * 768;
      float v = p.b1um[j];
#pragma unroll
      for (int ks = 0; ks < 6; ks++) v += p.TPU[(size_t)(ks * 48 + g * 16 + r) * 768 + j];
      xs[e] = v;
    }
    __syncthreads();
    softmax_rows(xs, 768);
    float2 ra, rb;
    mm_rows(xs, 768, 768, p.w2um, 768, jt * 128, ra, rb);
    int r0 = w * 2, j0 = jt * 128 + lane * 2, bi0 = g * 16 + r0;
    float b0 = p.b2um[j0], b1v = p.b2um[j0 + 1];
    float2 xc0 = *(const float2*)(p.XC + (size_t)bi0 * 768 + j0);
    float2 xc1 = *(const float2*)(p.XC + (size_t)(bi0 + 1) * 768 + j0);
    *(float2*)(p.XU2 + (size_t)bi0 * 768 + j0) =
        make_float2(xc0.x * (ra.x + b0), xc0.y * (ra.y + b1v));
    *(float2*)(p.XU2 + (size_t)(bi0 + 1) * 768 + j0) =
        make_float2(xc1.x * (rb.x + b0), xc1.y * (rb.y + b1v));
  }
  GSYNC();

  // ---- P7: xu2 @ W_um + bias + relu + u-gate -> RNEW. 6 blocks. ----
  if (bid < 6) {
    int g = bid >> 1, jt = bid & 1;
    const float* src = p.XU2 + (size_t)(g * 16) * 768;
    for (int e = tid; e < 12288; e += 512) xs[e] = src[e];
    __syncthreads();
    float2 ra, rb;
    mm_rows(xs, 768, 768, p.Wum, 256, jt * 128, ra, rb);
    int r0 = w * 2, j0 = jt * 128 + lane * 2, bi0 = g * 16 + r0;
    float bb0 = p.bum[j0], bb1 = p.bum[j0 + 1];
    float u0 = p.UPDW[bi0], u1 = p.UPDW[bi0 + 1];
    float2 xc0 = *(const float2*)(p.XC + (size_t)bi0 * 768 + j0);
    float2 xc1 = *(const float2*)(p.XC + (size_t)(bi0 + 1) * 768 + j0);
    *(float2*)(p.RNEW + (size_t)bi0 * 256 + j0) =
        make_float2(u0 * fmaxf(ra.x + bb0, 0.f) + (1.f - u0) * xc0.x,
                    u0 * fmaxf(ra.y + bb1, 0.f) + (1.f - u0) * xc0.y);
    *(float2*)(p.RNEW + (size_t)(bi0 + 1) * 256 + j0) =
        make_float2(u1 * fmaxf(rb.x + bb0, 0.f) + (1.f - u1) * xc1.x,
                    u1 * fmaxf(rb.y + bb1, 0.f) + (1.f - u1) * xc1.y);
  }
  GSYNC();

  // ---- Phase D: sequential fa_am chain through M ----
  for (int i = 0; i < 3; i++) {
    // D1: mm1 partials (K-split). 16 blocks.
    if (bid < 16) {
      int jt = bid & 3, ks = bid >> 2;
      for (int t = tid; t < 2048; t += 512) {
        int b = t >> 7, kk = t & 127;
        xs[t] = (ks < 2) ? p.RNEW[(size_t)(b * 3 + i) * 256 + ks * 128 + kk]
                         : p.M[b * 256 + (ks - 2) * 128 + kk];
      }
      __syncthreads();
      float2 ra, rb;
      mm_rows(xs, 128, 128, p.w1am + (size_t)(ks * 128) * 512, 512, jt * 128, ra, rb);
      store_tile16(p.TPM + (size_t)(ks * 16) * 512, 512, jt * 128, ra, rb);
    }
    GSYNC();
    // D2: softmax + mm2 + elementwise (XA = xc*(y+b2am)). 4 blocks.
    if (bid < 4) {
      int jt = bid;
      for (int e = tid; e < 8192; e += 512) {
        int b = e >> 9, j = e & 511;
        float v = p.b1am[j];
#pragma unroll
        for (int ks = 0; ks < 4; ks++) v += p.TPM[(size_t)(ks * 16 + b) * 512 + j];
        xs[e] = v;
      }
      __syncthreads();
      softmax_rows(xs, 512);
      float2 ra, rb;
      mm_rows(xs, 512, 512, p.w2am, 512, jt * 128, ra, rb);
      int r0 = w * 2, j0 = jt * 128 + lane * 2;
      float b0 = p.b2am[j0], b1v = p.b2am[j0 + 1];
      float2 c0, c1;
      if (j0 < 256) {
        c0 = *(const float2*)(p.RNEW + (size_t)(r0 * 3 + i) * 256 + j0);
        c1 = *(const float2*)(p.RNEW + (size_t)((r0 + 1) * 3 + i) * 256 + j0);
      } else {
        c0 = *(const float2*)(p.M + r0 * 256 + (j0 - 256));
        c1 = *(const float2*)(p.M + (r0 + 1) * 256 + (j0 - 256));
      }
      *(float2*)(p.XA + r0 * 512 + j0) =
          make_float2(c0.x * (ra.x + b0), c0.y * (ra.y + b1v));
      *(float2*)(p.XA + (r0 + 1) * 512 + j0) =
          make_float2(c1.x * (rb.x + b0), c1.y * (rb.y + b1v));
    }
    GSYNC();
    // D3: xa @ W_am + bias + relu, gate by readw -> M (and out on last). 2 blocks.
    if (bid < 2) {
      int jt = bid;
      for (int e = tid; e < 8192; e += 512) xs[e] = p.XA[e];
      __syncthreads();
      float2 ra, rb;
      mm_rows(xs, 512, 512, p.Wam, 256, jt * 128, ra, rb);
      int r0 = w * 2, j0 = jt * 128 + lane * 2;
      float bb0 = p.bam[j0], bb1 = p.bam[j0 + 1];
      float u0 = p.RDW[r0 * 3 + i], u1 = p.RDW[(r0 + 1) * 3 + i];
      float m00 = u0 * fmaxf(ra.x + bb0, 0.f), m01 = u0 * fmaxf(ra.y + bb1, 0.f);
      float m10 = u1 * fmaxf(rb.x + bb0, 0.f), m11 = u1 * fmaxf(rb.y + bb1, 0.f);
      *(float2*)(p.M + r0 * 256 + j0) = make_float2(m00, m01);
      *(float2*)(p.M + (r0 + 1) * 256 + j0) = make_float2(m10, m11);
      if (i == 2) {
        *(float2*)(p.out + r0 * 256 + j0) = make_float2(tanhf(m00), tanhf(m01));
        *(float2*)(p.out + (r0 + 1) * 256 + j0) = make_float2(tanhf(m10), tanhf(m11));
      }
    }
    if (i < 2) GSYNC();
  }
#undef GSYNC
}

__global__ void k_init(unsigned* bar) {
  if (threadIdx.x == 0) *bar = 0u;
}

// ---------------- launch ----------------
extern "C" void kernel_launch(void* const* d_in, const int* in_sizes, int n_in,
                              void* d_out, int out_size, void* d_ws, size_t ws_size,
                              hipStream_t stream) {
  float* ws = (float*)d_ws;
  Params p;
  p.x    = (const float*)d_in[0];
  p.mem  = (const float*)d_in[1];
  p.w1r  = (const float*)d_in[2];
  p.b1r  = (const float*)d_in[3];
  p.w2r  = (const float*)d_in[4];
  p.b2r  = (const float*)d_in[5];
  p.Wrd  = (const float*)d_in[6];
  p.brd  = (const float*)d_in[7];
  p.w1u  = (const float*)d_in[8];
  p.b1u  = (const float*)d_in[9];
  p.w2u  = (const float*)d_in[10];
  p.b2u  = (const float*)d_in[11];
  p.Wuw  = (const float*)d_in[12];
  p.buw  = (const float*)d_in[13];
  p.w1um = (const float*)d_in[14];
  p.b1um = (const float*)d_in[15];
  p.w2um = (const float*)d_in[16];
  p.b2um = (const float*)d_in[17];
  p.Wum  = (const float*)d_in[18];
  p.bum  = (const float*)d_in[19];
  p.w1am = (const float*)d_in[20];
  p.b1am = (const float*)d_in[21];
  p.w2am = (const float*)d_in[22];
  p.b2am = (const float*)d_in[23];
  p.Wam  = (const float*)d_in[24];
  p.bam  = (const float*)d_in[25];
  p.XR   = ws + WS_XR;
  p.XU   = ws + WS_XU;
  p.UPDW = ws + WS_UPDW;
  p.RDW  = ws + WS_READW;
  p.PMAX = ws + WS_PMAX;
  p.PIDX = (int*)(ws + WS_PIDX);
  p.RNEW = ws + WS_RNEW;
  p.M    = ws + WS_M;
  p.XC   = ws + WS_XC;
  p.TPA  = ws + WS_TPA;
  p.TPU  = ws + WS_TPU;
  p.XU2  = ws + WS_XU2;
  p.TPM  = ws + WS_TPM;
  p.XA   = ws + WS_XA;
  p.out  = (float*)d_out;
  unsigned* bar = (unsigned*)(ws + WS_BAR);

  hipLaunchKernelGGL(k_init, dim3(1), dim3(64), 0, stream, bar);
  void* kargs[] = { (void*)&p, (void*)&bar };
  hipLaunchCooperativeKernel((void*)mega, dim3(256), dim3(512), kargs, 0, stream);
}

// Round 3
// 1506.364 us; speedup vs baseline: 1.2413x; 1.2413x over previous
//
#include <hip/hip_runtime.h>
#include <cfloat>
#include <cmath>

constexpr int NTILES = 79;   // ceil(10000 / 128) for the read matmul

// ---------------- workspace layout (float offsets) ----------------
enum : int {
  WS_XR    = 0,        // 16*512
  WS_UPDW  = 8192,     // 48
  WS_READW = 8240,     // 48
  WS_PMAX  = 8288,     // 3*16*79
  WS_PIDX  = 12080,    // 3*16*79 (ints)
  WS_RNEW  = 15872,    // 48*256
  WS_M     = 28160,    // 16*256
  WS_XC    = 32256,    // 48*768
  WS_TPA   = 69120,    // 2*4*16*512  phase-A logit partials
  WS_BAR   = 134656,   // grid barrier counter (1 uint)
  WS_XU    = 151040,   // 16*512  x*(fa_u output)
  WS_TPU   = 216576,   // 6*48*768
  WS_XU2   = 474624,   // 48*768  xc*(fa_um y+b2)
  WS_TPM   = 769536,   // 4*16*512
  WS_XA    = 810496,   // 16*512  xc*(fa_am y+b2)
};

struct Params {
  const float *x, *mem;
  const float *w1r, *b1r, *w2r, *b2r, *Wrd, *brd;
  const float *w1u, *b1u, *w2u, *b2u, *Wuw, *buw;
  const float *w1um, *b1um, *w2um, *b2um, *Wum, *bum;
  const float *w1am, *b1am, *w2am, *b2am, *Wam, *bam;
  float *XR, *XU, *UPDW, *RDW, *PMAX;
  int   *PIDX;
  float *RNEW, *M, *XC, *TPA, *TPU, *XU2, *TPM, *XA, *out;
};

// ------- agent-scope relaxed atomic accessors (go to coherence point, ---
// ------- bypass stale L1/L2; no wbl2/inv cache maintenance needed) ------
__device__ __forceinline__ void st4(float* p, float v) {
  __hip_atomic_store(p, v, __ATOMIC_RELAXED, __HIP_MEMORY_SCOPE_AGENT);
}
__device__ __forceinline__ float ld4(const float* p) {
  return __hip_atomic_load((float*)p, __ATOMIC_RELAXED, __HIP_MEMORY_SCOPE_AGENT);
}
__device__ __forceinline__ void st4i(int* p, int v) {
  __hip_atomic_store(p, v, __ATOMIC_RELAXED, __HIP_MEMORY_SCOPE_AGENT);
}
__device__ __forceinline__ int ld4i(const int* p) {
  return __hip_atomic_load((int*)p, __ATOMIC_RELAXED, __HIP_MEMORY_SCOPE_AGENT);
}
__device__ __forceinline__ void st8(float* p, float2 v) {
  union { float2 f; unsigned long long u; } c; c.f = v;
  __hip_atomic_store((unsigned long long*)p, c.u, __ATOMIC_RELAXED, __HIP_MEMORY_SCOPE_AGENT);
}
__device__ __forceinline__ float2 ld8(const float* p) {
  union { float2 f; unsigned long long u; } c;
  c.u = __hip_atomic_load((unsigned long long*)p, __ATOMIC_RELAXED, __HIP_MEMORY_SCOPE_AGENT);
  return c.f;
}

// ---------------- reductions (wave = 64) ----------------
__device__ __forceinline__ float wave_sum(float v) {
#pragma unroll
  for (int o = 32; o > 0; o >>= 1) v += __shfl_xor(v, o);
  return v;
}
__device__ __forceinline__ float wave_max(float v) {
#pragma unroll
  for (int o = 32; o > 0; o >>= 1) v = fmaxf(v, __shfl_xor(v, o));
  return v;
}
__device__ __forceinline__ float block_sum(float v, float* red) {
  int lane = threadIdx.x & 63, w = threadIdx.x >> 6, nw = blockDim.x >> 6;
  v = wave_sum(v);
  __syncthreads();
  if (lane == 0) red[w] = v;
  __syncthreads();
  float s = 0.f;
  for (int k = 0; k < nw; k++) s += red[k];
  return s;
}

// ---------------- relaxed producer/consumer grid flags ----------------
// Monotonic arrival counter at LLC. Writers arrive (after __syncthreads
// drains their stores, which are themselves agent-scope atomics → already
// at the coherence point). Readers spin with RELAXED loads — NO cache
// invalidates, so L2 stays warm with weights.
__device__ __forceinline__ void bar_arrive(unsigned* bar) {
  __syncthreads();
  asm volatile("" ::: "memory");
  if (threadIdx.x == 0)
    __hip_atomic_fetch_add(bar, 1u, __ATOMIC_RELAXED, __HIP_MEMORY_SCOPE_AGENT);
}
__device__ __forceinline__ void bar_wait(unsigned* bar, unsigned tgt) {
  if (threadIdx.x == 0) {
    while (__hip_atomic_load(bar, __ATOMIC_RELAXED, __HIP_MEMORY_SCOPE_AGENT) < tgt)
      __builtin_amdgcn_s_sleep(8);
  }
  asm volatile("" ::: "memory");
  __syncthreads();
}

// ---------------- mm core ----------------
// 512 thr = 8 waves; wave w -> rows (2w,2w+1); lane -> 2 consecutive cols.
// unroll 32 => 32 outstanding weight loads per lane (latency-chain killer).
__device__ __forceinline__ void mm_rows(const float* __restrict__ xs, int ldx, int K,
                                        const float* __restrict__ W, int ldw, int jbase,
                                        float2& ra, float2& rb) {
  int lane = threadIdx.x & 63, w = threadIdx.x >> 6;
  const float* xa = xs + (w * 2) * ldx;
  const float* xb = xa + ldx;
  const float* Wp = W + jbase + lane * 2;
  float a00 = 0.f, a01 = 0.f, a10 = 0.f, a11 = 0.f;
#pragma unroll 32
  for (int k = 0; k < K; k++) {
    float2 wv = *(const float2*)(Wp + (size_t)k * ldw);
    float xav = xa[k], xbv = xb[k];
    a00 = fmaf(xav, wv.x, a00); a01 = fmaf(xav, wv.y, a01);
    a10 = fmaf(xbv, wv.x, a10); a11 = fmaf(xbv, wv.y, a11);
  }
  ra = make_float2(a00, a01);
  rb = make_float2(a10, a11);
}
// store a 16x128 tile to global via relaxed-atomic float2
__device__ __forceinline__ void store_tile16_at(float* T, int ldt, int jbase,
                                                float2 ra, float2 rb) {
  int lane = threadIdx.x & 63, w = threadIdx.x >> 6;
  int r0 = w * 2, j0 = jbase + lane * 2;
  st8(T + (size_t)r0 * ldt + j0, ra);
  st8(T + (size_t)(r0 + 1) * ldt + j0, rb);
}

// Per-wave in-place softmax of rows 2w,2w+1 of a 16-row LDS tile.
__device__ __forceinline__ void softmax_rows(float* xs, int ncol) {
  int lane = threadIdx.x & 63, w = threadIdx.x >> 6;
#pragma unroll
  for (int rr = 0; rr < 2; rr++) {
    float* row = xs + (size_t)(w * 2 + rr) * ncol;
    float mx = -FLT_MAX;
    for (int j = lane; j < ncol; j += 64) mx = fmaxf(mx, row[j]);
    mx = wave_max(mx);
    float acc = 0.f;
    for (int j = lane; j < ncol; j += 64) {
      float e = expf(row[j] - mx);
      row[j] = e;
      acc += e;
    }
    acc = wave_sum(acc);
    float inv = 1.f / acc;
    for (int j = lane; j < ncol; j += 64) row[j] *= inv;
  }
}

// Cumulative barrier targets (participants who ARRIVE at each boundary)
//  b1:P1=32  b2:P2=8  b3:P3=253  b4:P4=48  b5:P5=108  b6:P6=18  b7:P7=6
//  then D: per i {D1=16, D2=4, D3=2}
enum : unsigned {
  T1 = 32, T2 = 40, T3 = 293, T4 = 341, T5 = 449, T6 = 467, T7 = 473
};

// ================= the mega-kernel =================
__global__ __launch_bounds__(512, 2) void mega(Params p, unsigned* bar) {
  __shared__ __align__(16) float xs[12288];   // 48 KB: 16x768 max tile
  __shared__ float red[16];
  __shared__ int sidx;
  const int bid = blockIdx.x, tid = threadIdx.x;
  const int lane = tid & 63, w = tid >> 6;

  // ---- P1: fa_r/fa_u mm1 partials (K-split). 32 blocks. ----
  if (bid < 32) {
    int jt = bid & 3, ks = (bid >> 2) & 3, m = bid >> 4;
    for (int t = tid; t < 2048; t += 512) {
      int b = t >> 7, kk = t & 127;
      xs[t] = p.x[b * 512 + ks * 128 + kk];
    }
    __syncthreads();
    float2 ra, rb;
    mm_rows(xs, 128, 128, (m ? p.w1u : p.w1r) + (size_t)(ks * 128) * 512, 512, jt * 128, ra, rb);
    store_tile16_at(p.TPA + (size_t)((m * 4 + ks) * 16) * 512, 512, jt * 128, ra, rb);
    bar_arrive(bar);
  }

  // ---- P2: assemble logits + softmax + mm2 + elementwise. 8 blocks. ----
  if (bid < 8) {
    bar_wait(bar, T1);
    int m = bid >> 2, jt = bid & 3;
    const float* b1 = m ? p.b1u : p.b1r;
#pragma unroll 4
    for (int e = tid; e < 8192; e += 512) {
      int b = e >> 9, j = e & 511;
      float v = b1[j];
#pragma unroll
      for (int ks = 0; ks < 4; ks++) v += ld4(&p.TPA[(size_t)((m * 4 + ks) * 16 + b) * 512 + j]);
      xs[e] = v;
    }
    __syncthreads();
    softmax_rows(xs, 512);
    float2 ra, rb;
    mm_rows(xs, 512, 512, m ? p.w2u : p.w2r, 512, jt * 128, ra, rb);
    int r0 = w * 2, j0 = jt * 128 + lane * 2;
    const float* b2 = m ? p.b2u : p.b2r;
    float b20 = b2[j0], b21 = b2[j0 + 1];
    float* dst = m ? p.XU : p.XR;
    float2 x0 = *(const float2*)(p.x + r0 * 512 + j0);
    float2 x1 = *(const float2*)(p.x + (r0 + 1) * 512 + j0);
    st8(dst + r0 * 512 + j0,       make_float2(x0.x * (ra.x + b20), x0.y * (ra.y + b21)));
    st8(dst + (r0 + 1) * 512 + j0, make_float2(x1.x * (rb.x + b20), x1.y * (rb.y + b21)));
    bar_arrive(bar);
  }

  // ---- P3: read matmul (0..236)  ||  UPDW sigmoid + M-zero (240..255) ----
  if (bid < 237) {
    bar_wait(bar, T2);
    int ii = bid / NTILES, tile = bid % NTILES;
    {
      float2* d2 = (float2*)xs;
#pragma unroll 8
      for (int t = tid; t < 4096; t += 512) d2[t] = ld8(p.XR + 2 * t);
    }
    __syncthreads();
    int b0 = w * 2, b1 = b0 + 1;
    int s0 = tile * 128 + lane * 2;
    int sC = (s0 > 9998) ? 9998 : s0;
    const float* Wp = p.Wrd + ii * 10000 + sC;
    const float* xap = xs + b0 * 512;
    const float* xbp = xs + b1 * 512;
    float a00 = 0.f, a01 = 0.f, a10 = 0.f, a11 = 0.f;
#pragma unroll 8
    for (int c = 0; c < 512; c += 4) {
      float4 xa = *(const float4*)(xap + c);
      float4 xb = *(const float4*)(xbp + c);
      float2 w0 = *(const float2*)(Wp + (size_t)(c + 0) * 30000);
      float2 w1 = *(const float2*)(Wp + (size_t)(c + 1) * 30000);
      float2 w2 = *(const float2*)(Wp + (size_t)(c + 2) * 30000);
      float2 w3 = *(const float2*)(Wp + (size_t)(c + 3) * 30000);
      a00 = fmaf(xa.x, w0.x, a00); a01 = fmaf(xa.x, w0.y, a01);
      a10 = fmaf(xb.x, w0.x, a10); a11 = fmaf(xb.x, w0.y, a11);
      a00 = fmaf(xa.y, w1.x, a00); a01 = fmaf(xa.y, w1.y, a01);
      a10 = fmaf(xb.y, w1.x, a10); a11 = fmaf(xb.y, w1.y, a11);
      a00 = fmaf(xa.z, w2.x, a00); a01 = fmaf(xa.z, w2.y, a01);
      a10 = fmaf(xb.z, w2.x, a10); a11 = fmaf(xb.z, w2.y, a11);
      a00 = fmaf(xa.w, w3.x, a00); a01 = fmaf(xa.w, w3.y, a01);
      a10 = fmaf(xb.w, w3.x, a10); a11 = fmaf(xb.w, w3.y, a11);
    }
    float2 bb = *(const float2*)(p.brd + ii * 10000 + sC);
    bool ok0 = (s0 < 10000), ok1 = (s0 + 1 < 10000);
    float v00 = a00 + bb.x, v01 = a01 + bb.y;
    float v10 = a10 + bb.x, v11 = a11 + bb.y;
    float bv0 = ok0 ? v00 : -FLT_MAX; int bi0 = s0;
    if (ok1 && v01 > bv0) { bv0 = v01; bi0 = s0 + 1; }
    float bv1 = ok0 ? v10 : -FLT_MAX; int bi1 = s0;
    if (ok1 && v11 > bv1) { bv1 = v11; bi1 = s0 + 1; }
#pragma unroll
    for (int o = 32; o > 0; o >>= 1) {
      float ov = __shfl_down(bv0, o); int oi = __shfl_down(bi0, o);
      if (ov > bv0) { bv0 = ov; bi0 = oi; }
      ov = __shfl_down(bv1, o); oi = __shfl_down(bi1, o);
      if (ov > bv1) { bv1 = ov; bi1 = oi; }
    }
    if (lane == 0) {
      int base = (ii * 16 + b0) * NTILES + tile;
      st4(&p.PMAX[base], bv0); st4i(&p.PIDX[base], bi0);
      base = (ii * 16 + b1) * NTILES + tile;
      st4(&p.PMAX[base], bv1); st4i(&p.PIDX[base], bi1);
    }
    bar_arrive(bar);
  } else if (bid >= 240) {
    bar_wait(bar, T2);
    int b = bid - 240;
    float xu = ld4(&p.XU[b * 512 + tid]);
    if (tid < 256) st4(&p.M[b * 256 + tid], 0.f);
    for (int i2 = 0; i2 < 3; i2++) {
      float si = block_sum(xu * p.Wuw[tid * 3 + i2], red);
      if (tid == 0) st4(&p.UPDW[b * 3 + i2], 1.f / (1.f + expf(-(si + p.buw[i2]))));
    }
    bar_arrive(bar);
  }

  // ---- P4: argmax finalize + gather XC = [mem_row, x]. 48 blocks. ----
  if (bid < 48) {
    bar_wait(bar, T3);
    int b = bid / 3, ii = bid % 3;
    if (tid < 64) {
      float bv = -FLT_MAX; int bix = 0;
      const float* pm = p.PMAX + (ii * 16 + b) * NTILES;
      const int* pi = p.PIDX + (ii * 16 + b) * NTILES;
      for (int t = lane; t < NTILES; t += 64) {
        float v = ld4(&pm[t]); int ix = ld4i(&pi[t]);
        if (v > bv || (v == bv && ix < bix)) { bv = v; bix = ix; }
      }
#pragma unroll
      for (int o = 32; o > 0; o >>= 1) {
        float ov = __shfl_down(bv, o); int oi = __shfl_down(bix, o);
        if (ov > bv || (ov == bv && oi < bix)) { bv = ov; bix = oi; }
      }
      if (lane == 0) { sidx = bix; st4(&p.RDW[bid], tanhf(bv)); }
    }
    __syncthreads();
    for (int t = tid; t < 768; t += 512)
      st4(&p.XC[(size_t)bid * 768 + t], (t < 256)
          ? p.mem[((size_t)b * 10000 + sidx) * 256 + t]
          : p.x[b * 512 + (t - 256)]);
    bar_arrive(bar);
  }

  // ---- P5: fa_um mm1 partials (K-split). 108 blocks. ----
  if (bid < 108) {
    bar_wait(bar, T4);
    int jt = bid % 6, ks = (bid / 6) % 6, g = bid / 36;
#pragma unroll 4
    for (int t = tid; t < 2048; t += 512) {
      int r = t >> 7, kk = t & 127;
      xs[t] = ld4(&p.XC[(size_t)(g * 16 + r) * 768 + ks * 128 + kk]);
    }
    __syncthreads();
    float2 ra, rb;
    mm_rows(xs, 128, 128, p.w1um + (size_t)(ks * 128) * 768, 768, jt * 128, ra, rb);
    store_tile16_at(p.TPU + (size_t)(ks * 48 + g * 16) * 768, 768, jt * 128, ra, rb);
    bar_arrive(bar);
  }

  // ---- P6: fa_um softmax + mm2 + elementwise (XU2). 18 blocks. ----
  if (bid < 18) {
    bar_wait(bar, T5);
    int g = bid / 6, jt = bid % 6;
#pragma unroll 4
    for (int e = tid; e < 12288; e += 512) {
      int r = e / 768, j = e - r * 768;
      float v = p.b1um[j];
#pragma unroll
      for (int ks = 0; ks < 6; ks++) v += ld4(&p.TPU[(size_t)(ks * 48 + g * 16 + r) * 768 + j]);
      xs[e] = v;
    }
    __syncthreads();
    softmax_rows(xs, 768);
    float2 ra, rb;
    mm_rows(xs, 768, 768, p.w2um, 768, jt * 128, ra, rb);
    int r0 = w * 2, j0 = jt * 128 + lane * 2, bi0 = g * 16 + r0;
    float b0 = p.b2um[j0], b1v = p.b2um[j0 + 1];
    float2 xc0 = ld8(&p.XC[(size_t)bi0 * 768 + j0]);
    float2 xc1 = ld8(&p.XC[(size_t)(bi0 + 1) * 768 + j0]);
    st8(&p.XU2[(size_t)bi0 * 768 + j0],
        make_float2(xc0.x * (ra.x + b0), xc0.y * (ra.y + b1v)));
    st8(&p.XU2[(size_t)(bi0 + 1) * 768 + j0],
        make_float2(xc1.x * (rb.x + b0), xc1.y * (rb.y + b1v)));
    bar_arrive(bar);
  }

  // ---- P7: xu2 @ W_um + bias + relu + u-gate -> RNEW. 6 blocks. ----
  if (bid < 6) {
    bar_wait(bar, T6);
    int g = bid >> 1, jt = bid & 1;
    const float* src = p.XU2 + (size_t)(g * 16) * 768;
#pragma unroll 8
    for (int e = tid; e < 12288; e += 512) xs[e] = ld4(&src[e]);
    __syncthreads();
    float2 ra, rb;
    mm_rows(xs, 768, 768, p.Wum, 256, jt * 128, ra, rb);
    int r0 = w * 2, j0 = jt * 128 + lane * 2, bi0 = g * 16 + r0;
    float bb0 = p.bum[j0], bb1 = p.bum[j0 + 1];
    float u0 = ld4(&p.UPDW[bi0]), u1 = ld4(&p.UPDW[bi0 + 1]);
    float2 xc0 = ld8(&p.XC[(size_t)bi0 * 768 + j0]);
    float2 xc1 = ld8(&p.XC[(size_t)(bi0 + 1) * 768 + j0]);
    st8(&p.RNEW[(size_t)bi0 * 256 + j0],
        make_float2(u0 * fmaxf(ra.x + bb0, 0.f) + (1.f - u0) * xc0.x,
                    u0 * fmaxf(ra.y + bb1, 0.f) + (1.f - u0) * xc0.y));
    st8(&p.RNEW[(size_t)(bi0 + 1) * 256 + j0],
        make_float2(u1 * fmaxf(rb.x + bb0, 0.f) + (1.f - u1) * xc1.x,
                    u1 * fmaxf(rb.y + bb1, 0.f) + (1.f - u1) * xc1.y));
    bar_arrive(bar);
  }

  // ---- Phase D: sequential fa_am chain through M. Blocks 0..15 only. ----
  if (bid < 16) {
    unsigned T = T7;
    for (int i = 0; i < 3; i++) {
      // D1: mm1 partials (K-split). 16 blocks.
      bar_wait(bar, T);
      {
        int jt = bid & 3, ks = bid >> 2;
#pragma unroll 4
        for (int t = tid; t < 2048; t += 512) {
          int b = t >> 7, kk = t & 127;
          xs[t] = (ks < 2) ? ld4(&p.RNEW[(size_t)(b * 3 + i) * 256 + ks * 128 + kk])
                           : ld4(&p.M[b * 256 + (ks - 2) * 128 + kk]);
        }
        __syncthreads();
        float2 ra, rb;
        mm_rows(xs, 128, 128, p.w1am + (size_t)(ks * 128) * 512, 512, jt * 128, ra, rb);
        store_tile16_at(p.TPM + (size_t)(ks * 16) * 512, 512, jt * 128, ra, rb);
      }
      bar_arrive(bar); T += 16;

      // D2: softmax + mm2 + elementwise (XA). 4 blocks.
      if (bid < 4) {
        bar_wait(bar, T);
        int jt = bid;
#pragma unroll 4
        for (int e = tid; e < 8192; e += 512) {
          int b = e >> 9, j = e & 511;
          float v = p.b1am[j];
#pragma unroll
          for (int ks = 0; ks < 4; ks++) v += ld4(&p.TPM[(size_t)(ks * 16 + b) * 512 + j]);
          xs[e] = v;
        }
        __syncthreads();
        softmax_rows(xs, 512);
        float2 ra, rb;
        mm_rows(xs, 512, 512, p.w2am, 512, jt * 128, ra, rb);
        int r0 = w * 2, j0 = jt * 128 + lane * 2;
        float b0 = p.b2am[j0], b1v = p.b2am[j0 + 1];
        float2 c0, c1;
        if (j0 < 256) {
          c0 = ld8(&p.RNEW[(size_t)(r0 * 3 + i) * 256 + j0]);
          c1 = ld8(&p.RNEW[(size_t)((r0 + 1) * 3 + i) * 256 + j0]);
        } else {
          c0 = ld8(&p.M[r0 * 256 + (j0 - 256)]);
          c1 = ld8(&p.M[(r0 + 1) * 256 + (j0 - 256)]);
        }
        st8(&p.XA[r0 * 512 + j0],
            make_float2(c0.x * (ra.x + b0), c0.y * (ra.y + b1v)));
        st8(&p.XA[(r0 + 1) * 512 + j0],
            make_float2(c1.x * (rb.x + b0), c1.y * (rb.y + b1v)));
        bar_arrive(bar);
      }
      T += 4;

      // D3: xa @ W_am + bias + relu, gate -> M (and out on last). 2 blocks.
      if (bid < 2) {
        bar_wait(bar, T);
        int jt = bid;
#pragma unroll 8
        for (int e = tid; e < 8192; e += 512) xs[e] = ld4(&p.XA[e]);
        __syncthreads();
        float2 ra, rb;
        mm_rows(xs, 512, 512, p.Wam, 256, jt * 128, ra, rb);
        int r0 = w * 2, j0 = jt * 128 + lane * 2;
        float bb0 = p.bam[j0], bb1 = p.bam[j0 + 1];
        float u0 = ld4(&p.RDW[r0 * 3 + i]), u1 = ld4(&p.RDW[(r0 + 1) * 3 + i]);
        float m00 = u0 * fmaxf(ra.x + bb0, 0.f), m01 = u0 * fmaxf(ra.y + bb1, 0.f);
        float m10 = u1 * fmaxf(rb.x + bb0, 0.f), m11 = u1 * fmaxf(rb.y + bb1, 0.f);
        st8(&p.M[r0 * 256 + j0], make_float2(m00, m01));
        st8(&p.M[(r0 + 1) * 256 + j0], make_float2(m10, m11));
        if (i == 2) {
          *(float2*)(p.out + r0 * 256 + j0) = make_float2(tanhf(m00), tanhf(m01));
          *(float2*)(p.out + (r0 + 1) * 256 + j0) = make_float2(tanhf(m10), tanhf(m11));
        }
        if (i < 2) bar_arrive(bar);
      }
      T += 2;
    }
  }
}

__global__ void k_init(unsigned* bar) {
  if (threadIdx.x == 0)
    __hip_atomic_store(bar, 0u, __ATOMIC_RELAXED, __HIP_MEMORY_SCOPE_AGENT);
}

// ---------------- launch ----------------
extern "C" void kernel_launch(void* const* d_in, const int* in_sizes, int n_in,
                              void* d_out, int out_size, void* d_ws, size_t ws_size,
                              hipStream_t stream) {
  float* ws = (float*)d_ws;
  Params p;
  p.x    = (const float*)d_in[0];
  p.mem  = (const float*)d_in[1];
  p.w1r  = (const float*)d_in[2];
  p.b1r  = (const float*)d_in[3];
  p.w2r  = (const float*)d_in[4];
  p.b2r  = (const float*)d_in[5];
  p.Wrd  = (const float*)d_in[6];
  p.brd  = (const float*)d_in[7];
  p.w1u  = (const float*)d_in[8];
  p.b1u  = (const float*)d_in[9];
  p.w2u  = (const float*)d_in[10];
  p.b2u  = (const float*)d_in[11];
  p.Wuw  = (const float*)d_in[12];
  p.buw  = (const float*)d_in[13];
  p.w1um = (const float*)d_in[14];
  p.b1um = (const float*)d_in[15];
  p.w2um = (const float*)d_in[16];
  p.b2um = (const float*)d_in[17];
  p.Wum  = (const float*)d_in[18];
  p.bum  = (const float*)d_in[19];
  p.w1am = (const float*)d_in[20];
  p.b1am = (const float*)d_in[21];
  p.w2am = (const float*)d_in[22];
  p.b2am = (const float*)d_in[23];
  p.Wam  = (const float*)d_in[24];
  p.bam  = (const float*)d_in[25];
  p.XR   = ws + WS_XR;
  p.XU   = ws + WS_XU;
  p.UPDW = ws + WS_UPDW;
  p.RDW  = ws + WS_READW;
  p.PMAX = ws + WS_PMAX;
  p.PIDX = (int*)(ws + WS_PIDX);
  p.RNEW = ws + WS_RNEW;
  p.M    = ws + WS_M;
  p.XC   = ws + WS_XC;
  p.TPA  = ws + WS_TPA;
  p.TPU  = ws + WS_TPU;
  p.XU2  = ws + WS_XU2;
  p.TPM  = ws + WS_TPM;
  p.XA   = ws + WS_XA;
  p.out  = (float*)d_out;
  unsigned* bar = (unsigned*)(ws + WS_BAR);

  hipLaunchKernelGGL(k_init, dim3(1), dim3(64), 0, stream, bar);
  void* kargs[] = { (void*)&p, (void*)&bar };
  hipLaunchCooperativeKernel((void*)mega, dim3(256), dim3(512), kargs, 0, stream);
}

// Round 4
// 1198.898 us; speedup vs baseline: 1.5596x; 1.2565x over previous
//
#include <hip/hip_runtime.h>
#include <cfloat>
#include <cmath>

constexpr int NTILES = 79;   // ceil(10000 / 128) for the read matmul

// ---------------- workspace layout (float offsets) ----------------
enum : int {
  WS_XR    = 0,        // 16*512
  WS_UPDW  = 8192,     // 48
  WS_READW = 8240,     // 48
  WS_PMAX  = 8288,     // 3*16*79
  WS_PIDX  = 12080,    // 3*16*79 (ints)
  WS_RNEW  = 15872,    // 48*256
  WS_M     = 28160,    // 16*256
};                     // total 32256 floats ~ 129 KB

// ---------------- reductions (wave = 64) ----------------
__device__ __forceinline__ float wave_sum(float v) {
#pragma unroll
  for (int o = 32; o > 0; o >>= 1) v += __shfl_xor(v, o);
  return v;
}
__device__ __forceinline__ float wave_max(float v) {
#pragma unroll
  for (int o = 32; o > 0; o >>= 1) v = fmaxf(v, __shfl_xor(v, o));
  return v;
}
__device__ __forceinline__ float block_sum(float v, float* red) {
  int lane = threadIdx.x & 63, w = threadIdx.x >> 6, nw = blockDim.x >> 6;
  v = wave_sum(v);
  __syncthreads();
  if (lane == 0) red[w] = v;
  __syncthreads();
  float s = 0.f;
  for (int k = 0; k < nw; k++) s += red[k];
  return s;
}
__device__ __forceinline__ float block_max(float v, float* red) {
  int lane = threadIdx.x & 63, w = threadIdx.x >> 6, nw = blockDim.x >> 6;
  v = wave_max(v);
  __syncthreads();
  if (lane == 0) red[w] = v;
  __syncthreads();
  float s = -FLT_MAX;
  for (int k = 0; k < nw; k++) s = fmaxf(s, red[k]);
  return s;
}

// ============ kA: fa_r (m=0) and fa_u + UPDW (m=1), one block per (m,b) ====
// Row-per-block: thread j owns output column j; full K=512 in-block.
__global__ __launch_bounds__(512) void kA(
    const float* __restrict__ x,
    const float* __restrict__ w1r, const float* __restrict__ b1r,
    const float* __restrict__ w2r, const float* __restrict__ b2r,
    const float* __restrict__ w1u, const float* __restrict__ b1u,
    const float* __restrict__ w2u, const float* __restrict__ b2u,
    const float* __restrict__ Wuw, const float* __restrict__ buw,
    float* __restrict__ XR, float* __restrict__ UPDW) {
  __shared__ float xl[512], hl[512], red[16];
  int bid = blockIdx.x, m = bid >> 4, b = bid & 15, tid = threadIdx.x;
  const float* w1 = m ? w1u : w1r;  const float* b1 = m ? b1u : b1r;
  const float* w2 = m ? w2u : w2r;  const float* b2 = m ? b2u : b2r;
  float xv = x[b * 512 + tid];
  xl[tid] = xv;
  __syncthreads();
  // mm1: logits (2 accumulators break the dep chain)
  float a0 = 0.f, a1 = 0.f;
#pragma unroll 8
  for (int k = 0; k < 256; k++)   a0 = fmaf(xl[k], w1[(size_t)k * 512 + tid], a0);
#pragma unroll 8
  for (int k = 256; k < 512; k++) a1 = fmaf(xl[k], w1[(size_t)k * 512 + tid], a1);
  float v = a0 + a1 + b1[tid];
  // softmax (block-wide, 1 elem/thread)
  float mx = block_max(v, red);
  float e = expf(v - mx);
  float s = block_sum(e, red);
  hl[tid] = e / s;
  __syncthreads();
  // mm2
  float y0 = 0.f, y1 = 0.f;
#pragma unroll 8
  for (int k = 0; k < 256; k++)   y0 = fmaf(hl[k], w2[(size_t)k * 512 + tid], y0);
#pragma unroll 8
  for (int k = 256; k < 512; k++) y1 = fmaf(hl[k], w2[(size_t)k * 512 + tid], y1);
  float o = xv * (y0 + y1 + b2[tid]);
  if (m == 0) {
    XR[b * 512 + tid] = o;
  } else {
    __syncthreads();          // hl fully consumed by mm2
    hl[tid] = o;              // reuse hl as the xu row
    __syncthreads();
    for (int i = 0; i < 3; i++) {
      float si = block_sum(hl[tid] * Wuw[tid * 3 + i], red);
      if (tid == 0) UPDW[b * 3 + i] = 1.f / (1.f + expf(-(si + buw[i])));
    }
  }
}

// ============ kRead: read matmul + per-tile max/argmax (R0-verified) =======
__global__ __launch_bounds__(512) void k_read(
    const float* __restrict__ W, const float* __restrict__ brd,
    const float* __restrict__ xr,
    float* __restrict__ pmax, int* __restrict__ pidx) {
  __shared__ __align__(16) float xs[16 * 512];
  int tid = threadIdx.x, lane = tid & 63, w = tid >> 6;
  int i = blockIdx.y, tile = blockIdx.x;
  {
    const float4* s4 = (const float4*)xr;
    float4* d4 = (float4*)xs;
    for (int t = tid; t < 2048; t += 512) d4[t] = s4[t];
  }
  __syncthreads();
  int b0 = w * 2, b1 = b0 + 1;
  int s0 = tile * 128 + lane * 2;
  int sC = (s0 > 9998) ? 9998 : s0;
  const float* Wp = W + i * 10000 + sC;
  const float* xap = xs + b0 * 512;
  const float* xbp = xs + b1 * 512;
  float a00 = 0.f, a01 = 0.f, a10 = 0.f, a11 = 0.f;
#pragma unroll 8
  for (int c = 0; c < 512; c += 4) {
    float4 xa = *(const float4*)(xap + c);
    float4 xb = *(const float4*)(xbp + c);
    float2 w0 = *(const float2*)(Wp + (size_t)(c + 0) * 30000);
    float2 w1 = *(const float2*)(Wp + (size_t)(c + 1) * 30000);
    float2 w2 = *(const float2*)(Wp + (size_t)(c + 2) * 30000);
    float2 w3 = *(const float2*)(Wp + (size_t)(c + 3) * 30000);
    a00 = fmaf(xa.x, w0.x, a00); a01 = fmaf(xa.x, w0.y, a01);
    a10 = fmaf(xb.x, w0.x, a10); a11 = fmaf(xb.x, w0.y, a11);
    a00 = fmaf(xa.y, w1.x, a00); a01 = fmaf(xa.y, w1.y, a01);
    a10 = fmaf(xb.y, w1.x, a10); a11 = fmaf(xb.y, w1.y, a11);
    a00 = fmaf(xa.z, w2.x, a00); a01 = fmaf(xa.z, w2.y, a01);
    a10 = fmaf(xb.z, w2.x, a10); a11 = fmaf(xb.z, w2.y, a11);
    a00 = fmaf(xa.w, w3.x, a00); a01 = fmaf(xa.w, w3.y, a01);
    a10 = fmaf(xb.w, w3.x, a10); a11 = fmaf(xb.w, w3.y, a11);
  }
  float2 bb = *(const float2*)(brd + i * 10000 + sC);
  bool ok0 = (s0 < 10000), ok1 = (s0 + 1 < 10000);
  float v00 = a00 + bb.x, v01 = a01 + bb.y;
  float v10 = a10 + bb.x, v11 = a11 + bb.y;
  float bv0 = ok0 ? v00 : -FLT_MAX; int bi0 = s0;
  if (ok1 && v01 > bv0) { bv0 = v01; bi0 = s0 + 1; }
  float bv1 = ok0 ? v10 : -FLT_MAX; int bi1 = s0;
  if (ok1 && v11 > bv1) { bv1 = v11; bi1 = s0 + 1; }
#pragma unroll
  for (int o = 32; o > 0; o >>= 1) {
    float ov = __shfl_down(bv0, o); int oi = __shfl_down(bi0, o);
    if (ov > bv0) { bv0 = ov; bi0 = oi; }
    ov = __shfl_down(bv1, o); oi = __shfl_down(bi1, o);
    if (ov > bv1) { bv1 = ov; bi1 = oi; }
  }
  if (lane == 0) {
    int base = (i * 16 + b0) * NTILES + tile;
    pmax[base] = bv0; pidx[base] = bi0;
    base = (i * 16 + b1) * NTILES + tile;
    pmax[base] = bv1; pidx[base] = bi1;
  }
}

// ============ kC: argmax finalize + gather + full fa_um + W_um + gate ======
// One block per (b,i) row. K=768 fully in-block; nothing intermediate to HBM.
__global__ __launch_bounds__(512) void kC(
    const float* __restrict__ mem, const float* __restrict__ x,
    const float* __restrict__ pmax, const int* __restrict__ pidx,
    const float* __restrict__ w1um, const float* __restrict__ b1um,
    const float* __restrict__ w2um, const float* __restrict__ b2um,
    const float* __restrict__ Wum, const float* __restrict__ bum,
    const float* __restrict__ UPDW,
    float* __restrict__ RDW, float* __restrict__ RNEW) {
  __shared__ float xcl[768], hl[768], xul[768], part[512], red[16];
  __shared__ int sidx;
  int bid = blockIdx.x, b = bid / 3, i = bid % 3;
  int tid = threadIdx.x, lane = tid & 63;
  // argmax finalize over 79 tile-partials (wave 0)
  if (tid < 64) {
    float bv = -FLT_MAX; int bix = 0;
    const float* pm = pmax + (i * 16 + b) * NTILES;
    const int* pi = pidx + (i * 16 + b) * NTILES;
    for (int t = lane; t < NTILES; t += 64) {
      float v = pm[t]; int ix = pi[t];
      if (v > bv || (v == bv && ix < bix)) { bv = v; bix = ix; }
    }
#pragma unroll
    for (int o = 32; o > 0; o >>= 1) {
      float ov = __shfl_down(bv, o); int oi = __shfl_down(bix, o);
      if (ov > bv || (ov == bv && oi < bix)) { bv = ov; bix = oi; }
    }
    if (lane == 0) { sidx = bix; RDW[bid] = tanhf(bv); }
  }
  __syncthreads();
  // gather xc = [mem_row(256), x(512)]
  xcl[tid] = (tid < 256) ? mem[((size_t)b * 10000 + sidx) * 256 + tid]
                         : x[b * 512 + tid - 256];
  if (tid < 256) xcl[512 + tid] = x[b * 512 + 256 + tid];
  __syncthreads();
  // mm1: K=768, N=768 (thread owns cols tid and 512+tid for tid<256)
  float a0 = 0.f, a0b = 0.f, a1 = 0.f, a1b = 0.f;
#pragma unroll 8
  for (int k = 0; k < 384; k++) {
    float xk = xcl[k]; const float* Wr = w1um + (size_t)k * 768;
    a0 = fmaf(xk, Wr[tid], a0);
    if (tid < 256) a1 = fmaf(xk, Wr[512 + tid], a1);
  }
#pragma unroll 8
  for (int k = 384; k < 768; k++) {
    float xk = xcl[k]; const float* Wr = w1um + (size_t)k * 768;
    a0b = fmaf(xk, Wr[tid], a0b);
    if (tid < 256) a1b = fmaf(xk, Wr[512 + tid], a1b);
  }
  float v0 = a0 + a0b + b1um[tid];
  float v1 = (tid < 256) ? (a1 + a1b + b1um[512 + tid]) : -FLT_MAX;
  // softmax over 768
  float mx = block_max(fmaxf(v0, v1), red);
  float e0 = expf(v0 - mx);
  float e1 = (tid < 256) ? expf(v1 - mx) : 0.f;
  float s = block_sum(e0 + e1, red);
  float inv = 1.f / s;
  hl[tid] = e0 * inv;
  if (tid < 256) hl[512 + tid] = e1 * inv;
  __syncthreads();
  // mm2: K=768, N=768; xu2 = xc * (y + b2um)
  float y0 = 0.f, y0b = 0.f, y1 = 0.f, y1b = 0.f;
#pragma unroll 8
  for (int k = 0; k < 384; k++) {
    float hk = hl[k]; const float* Wr = w2um + (size_t)k * 768;
    y0 = fmaf(hk, Wr[tid], y0);
    if (tid < 256) y1 = fmaf(hk, Wr[512 + tid], y1);
  }
#pragma unroll 8
  for (int k = 384; k < 768; k++) {
    float hk = hl[k]; const float* Wr = w2um + (size_t)k * 768;
    y0b = fmaf(hk, Wr[tid], y0b);
    if (tid < 256) y1b = fmaf(hk, Wr[512 + tid], y1b);
  }
  xul[tid] = xcl[tid] * (y0 + y0b + b2um[tid]);
  if (tid < 256) xul[512 + tid] = xcl[512 + tid] * (y1 + y1b + b2um[512 + tid]);
  __syncthreads();
  // W_um: 768 -> 256, K split across thread halves
  int j = tid & 255, kh = tid >> 8;
  float acc = 0.f;
#pragma unroll 8
  for (int k = kh * 384; k < kh * 384 + 384; k++)
    acc = fmaf(xul[k], Wum[(size_t)k * 256 + j], acc);
  part[tid] = acc;
  __syncthreads();
  if (tid < 256) {
    float sf = part[tid] + part[tid + 256] + bum[tid];
    float u = UPDW[b * 3 + i];
    RNEW[(size_t)(b * 3 + i) * 256 + tid] =
        u * fmaxf(sf, 0.f) + (1.f - u) * xcl[tid];
  }
}

// ============ kD: full fa_am + W_am + gate -> M (and tanh out on last) =====
// One block per batch row b. i==0 uses literal zeros for M.
__global__ __launch_bounds__(512) void kD(
    const float* __restrict__ RNEW, const float* __restrict__ Mbuf,
    const float* __restrict__ w1am, const float* __restrict__ b1am,
    const float* __restrict__ w2am, const float* __restrict__ b2am,
    const float* __restrict__ Wam, const float* __restrict__ bam,
    const float* __restrict__ RDW, float* __restrict__ Mout,
    float* __restrict__ out, int i, int last) {
  __shared__ float xcl[512], hl[512], part[512], red[16];
  int b = blockIdx.x, tid = threadIdx.x;
  float xv = (tid < 256) ? RNEW[(size_t)(b * 3 + i) * 256 + tid]
                         : (i == 0 ? 0.f : Mbuf[b * 256 + tid - 256]);
  xcl[tid] = xv;
  __syncthreads();
  // mm1
  float a0 = 0.f, a1 = 0.f;
#pragma unroll 8
  for (int k = 0; k < 256; k++)   a0 = fmaf(xcl[k], w1am[(size_t)k * 512 + tid], a0);
#pragma unroll 8
  for (int k = 256; k < 512; k++) a1 = fmaf(xcl[k], w1am[(size_t)k * 512 + tid], a1);
  float v = a0 + a1 + b1am[tid];
  float mx = block_max(v, red);
  float e = expf(v - mx);
  float s = block_sum(e, red);
  hl[tid] = e / s;
  __syncthreads();
  // mm2 + elementwise
  float y0 = 0.f, y1 = 0.f;
#pragma unroll 8
  for (int k = 0; k < 256; k++)   y0 = fmaf(hl[k], w2am[(size_t)k * 512 + tid], y0);
#pragma unroll 8
  for (int k = 256; k < 512; k++) y1 = fmaf(hl[k], w2am[(size_t)k * 512 + tid], y1);
  float xa = xv * (y0 + y1 + b2am[tid]);
  __syncthreads();          // hl fully consumed
  hl[tid] = xa;             // reuse hl as xa row
  __syncthreads();
  // W_am: 512 -> 256, K split across thread halves
  int j = tid & 255, kh = tid >> 8;
  float acc = 0.f;
#pragma unroll 8
  for (int k = kh * 256; k < kh * 256 + 256; k++)
    acc = fmaf(hl[k], Wam[(size_t)k * 256 + j], acc);
  part[tid] = acc;
  __syncthreads();
  if (tid < 256) {
    float sf = part[tid] + part[tid + 256] + bam[tid];
    float mv = RDW[b * 3 + i] * fmaxf(sf, 0.f);
    Mout[b * 256 + tid] = mv;
    if (last) out[b * 256 + tid] = tanhf(mv);
  }
}

// ---------------- launch ----------------
extern "C" void kernel_launch(void* const* d_in, const int* in_sizes, int n_in,
                              void* d_out, int out_size, void* d_ws, size_t ws_size,
                              hipStream_t stream) {
  const float* x    = (const float*)d_in[0];
  const float* mem  = (const float*)d_in[1];
  const float* w1r  = (const float*)d_in[2];
  const float* b1r  = (const float*)d_in[3];
  const float* w2r  = (const float*)d_in[4];
  const float* b2r  = (const float*)d_in[5];
  const float* Wrd  = (const float*)d_in[6];
  const float* brd  = (const float*)d_in[7];
  const float* w1u  = (const float*)d_in[8];
  const float* b1u  = (const float*)d_in[9];
  const float* w2u  = (const float*)d_in[10];
  const float* b2u  = (const float*)d_in[11];
  const float* Wuw  = (const float*)d_in[12];
  const float* buw  = (const float*)d_in[13];
  const float* w1um = (const float*)d_in[14];
  const float* b1um = (const float*)d_in[15];
  const float* w2um = (const float*)d_in[16];
  const float* b2um = (const float*)d_in[17];
  const float* Wum  = (const float*)d_in[18];
  const float* bum  = (const float*)d_in[19];
  const float* w1am = (const float*)d_in[20];
  const float* b1am = (const float*)d_in[21];
  const float* w2am = (const float*)d_in[22];
  const float* b2am = (const float*)d_in[23];
  const float* Wam  = (const float*)d_in[24];
  const float* bam  = (const float*)d_in[25];

  float* ws   = (float*)d_ws;
  float* XR   = ws + WS_XR;
  float* UPDW = ws + WS_UPDW;
  float* RDW  = ws + WS_READW;
  float* PMAX = ws + WS_PMAX;
  int*   PIDX = (int*)(ws + WS_PIDX);
  float* RNEW = ws + WS_RNEW;
  float* M    = ws + WS_M;
  float* out  = (float*)d_out;

  kA    <<<32,                512, 0, stream>>>(x, w1r, b1r, w2r, b2r,
                                                w1u, b1u, w2u, b2u, Wuw, buw,
                                                XR, UPDW);
  k_read<<<dim3(NTILES, 3),   512, 0, stream>>>(Wrd, brd, XR, PMAX, PIDX);
  kC    <<<48,                512, 0, stream>>>(mem, x, PMAX, PIDX,
                                                w1um, b1um, w2um, b2um, Wum, bum,
                                                UPDW, RDW, RNEW);
  for (int i = 0; i < 3; i++)
    kD  <<<16,                512, 0, stream>>>(RNEW, M, w1am, b1am, w2am, b2am,
                                                Wam, bam, RDW, M, out, i, i == 2);
}

// Round 5
// 731.899 us; speedup vs baseline: 2.5547x; 1.6381x over previous
//
#include <hip/hip_runtime.h>
#include <cfloat>
#include <cmath>

constexpr int NTILES = 79;   // ceil(10000 / 128) for the read matmul

// ---------------- workspace layout (float offsets) ----------------
enum : int {
  WS_XR    = 0,        // 16*512
  WS_UPDW  = 8192,     // 48
  WS_READW = 8240,     // 48
  WS_PMAX  = 8288,     // 3*16*79
  WS_PIDX  = 12080,    // 3*16*79 (ints)
  WS_RNEW  = 15872,    // 48*256
  WS_M     = 28160,    // 16*256
  WS_XU    = 32256,    // 16*512
  WS_XA    = 40448,    // 16*512
  WS_TPA   = 48640,    // 2*4*16*512
  WS_TPM   = 114176,   // 4*16*512
  WS_XU2   = 146944,   // 48*768
  WS_TPU   = 183808,   // 6*48*768
  WS_XC    = 404992,   // 48*768
};                     // ends ~441856 floats (~1.7 MB)

// ---------------- reductions (wave = 64) ----------------
__device__ __forceinline__ float wave_sum(float v) {
#pragma unroll
  for (int o = 32; o > 0; o >>= 1) v += __shfl_xor(v, o);
  return v;
}
__device__ __forceinline__ float wave_max(float v) {
#pragma unroll
  for (int o = 32; o > 0; o >>= 1) v = fmaxf(v, __shfl_xor(v, o));
  return v;
}
__device__ __forceinline__ float block_sum(float v, float* red) {
  int lane = threadIdx.x & 63, w = threadIdx.x >> 6, nw = blockDim.x >> 6;
  v = wave_sum(v);
  __syncthreads();
  if (lane == 0) red[w] = v;
  __syncthreads();
  float s = 0.f;
  for (int k = 0; k < nw; k++) s += red[k];
  return s;
}

// ---------------- mm cores ----------------
// R0-verified: 512 thr = 8 waves; wave w -> rows (2w,2w+1); lane -> 2 cols.
// Fixed K=128 slice starting at koff of weight matrix W (row stride ldw).
__device__ __forceinline__ void mm_tile16(
    const float* __restrict__ xs,          // LDS [16][128]
    const float* __restrict__ W, int ldw, int koff, int jbase,
    float2& ra, float2& rb) {
  int lane = threadIdx.x & 63, w = threadIdx.x >> 6;
  const float* xa = xs + (w * 2) * 128;
  const float* xb = xa + 128;
  const float* Wp = W + (size_t)koff * ldw + jbase + lane * 2;
  float a00 = 0.f, a01 = 0.f, a10 = 0.f, a11 = 0.f;
#pragma unroll 8
  for (int k = 0; k < 128; k++) {
    float2 wv = *(const float2*)(Wp + (size_t)k * ldw);
    float xav = xa[k], xbv = xb[k];
    a00 = fmaf(xav, wv.x, a00); a01 = fmaf(xav, wv.y, a01);
    a10 = fmaf(xbv, wv.x, a10); a11 = fmaf(xbv, wv.y, a11);
  }
  ra = make_float2(a00, a01);
  rb = make_float2(a10, a11);
}
// Runtime-K variant, xs row stride ldx.
__device__ __forceinline__ void mm_rows(const float* __restrict__ xs, int ldx, int K,
                                        const float* __restrict__ W, int ldw, int jbase,
                                        float2& ra, float2& rb) {
  int lane = threadIdx.x & 63, w = threadIdx.x >> 6;
  const float* xa = xs + (w * 2) * ldx;
  const float* xb = xa + ldx;
  const float* Wp = W + jbase + lane * 2;
  float a00 = 0.f, a01 = 0.f, a10 = 0.f, a11 = 0.f;
#pragma unroll 16
  for (int k = 0; k < K; k++) {
    float2 wv = *(const float2*)(Wp + (size_t)k * ldw);
    float xav = xa[k], xbv = xb[k];
    a00 = fmaf(xav, wv.x, a00); a01 = fmaf(xav, wv.y, a01);
    a10 = fmaf(xbv, wv.x, a10); a11 = fmaf(xbv, wv.y, a11);
  }
  ra = make_float2(a00, a01);
  rb = make_float2(a10, a11);
}
__device__ __forceinline__ void store_tile16(
    float* __restrict__ T, int ldt, int jbase, float2 ra, float2 rb) {
  int lane = threadIdx.x & 63, w = threadIdx.x >> 6;
  int r0 = w * 2, j0 = jbase + lane * 2;
  *(float2*)(T + (size_t)r0 * ldt + j0) = ra;
  *(float2*)(T + (size_t)(r0 + 1) * ldt + j0) = rb;
}

// Per-wave in-place softmax of rows 2w,2w+1 of a 16-row LDS tile (stride ncol).
// Safe without a following __syncthreads: mm_rows wave w reads only rows 2w,2w+1.
__device__ __forceinline__ void softmax_rows(float* xs, int ncol) {
  int lane = threadIdx.x & 63, w = threadIdx.x >> 6;
#pragma unroll
  for (int rr = 0; rr < 2; rr++) {
    float* row = xs + (size_t)(w * 2 + rr) * ncol;
    float mx = -FLT_MAX;
    for (int j = lane; j < ncol; j += 64) mx = fmaxf(mx, row[j]);
    mx = wave_max(mx);
    float acc = 0.f;
    for (int j = lane; j < ncol; j += 64) {
      float e = expf(row[j] - mx);
      row[j] = e;
      acc += e;
    }
    acc = wave_sum(acc);
    float inv = 1.f / acc;
    for (int j = lane; j < ncol; j += 64) row[j] *= inv;
  }
}

// ================= A1: fa_r/fa_u mm1 partials. grid (4 jt, 4 ks, 2 m) ======
__global__ __launch_bounds__(512) void k_mm1_a(
    const float* __restrict__ x, const float* __restrict__ w1r,
    const float* __restrict__ w1u, float* __restrict__ TPA) {
  __shared__ float xs[16 * 128];
  int jt = blockIdx.x, ks = blockIdx.y, m = blockIdx.z, tid = threadIdx.x;
  for (int t = tid; t < 2048; t += 512) {
    int b = t >> 7, kk = t & 127;
    xs[t] = x[b * 512 + ks * 128 + kk];
  }
  __syncthreads();
  float2 ra, rb;
  mm_tile16(xs, m ? w1u : w1r, 512, ks * 128, jt * 128, ra, rb);
  store_tile16(TPA + (size_t)((m * 4 + ks) * 16) * 512, 512, jt * 128, ra, rb);
}

// ====== A2: assemble + softmax + mm2 + x*(..) -> XR/XU. grid (4 jt, 2 m) ===
__global__ __launch_bounds__(512) void k_sm2_a(
    const float* __restrict__ TPA, const float* __restrict__ x,
    const float* __restrict__ b1r, const float* __restrict__ b1u,
    const float* __restrict__ w2r, const float* __restrict__ w2u,
    const float* __restrict__ b2r, const float* __restrict__ b2u,
    float* __restrict__ XR, float* __restrict__ XU) {
  __shared__ float xs[8192];
  int jt = blockIdx.x, m = blockIdx.y, tid = threadIdx.x;
  int lane = tid & 63, w = tid >> 6;
  const float* b1 = m ? b1u : b1r;
  for (int e = tid; e < 8192; e += 512) {
    int b = e >> 9, j = e & 511;
    float v = b1[j];
#pragma unroll
    for (int ks = 0; ks < 4; ks++) v += TPA[(size_t)((m * 4 + ks) * 16 + b) * 512 + j];
    xs[e] = v;
  }
  __syncthreads();
  softmax_rows(xs, 512);
  float2 ra, rb;
  mm_rows(xs, 512, 512, m ? w2u : w2r, 512, jt * 128, ra, rb);
  int r0 = w * 2, j0 = jt * 128 + lane * 2;
  const float* b2 = m ? b2u : b2r;
  float b20 = b2[j0], b21 = b2[j0 + 1];
  float* dst = m ? XU : XR;
  float2 x0 = *(const float2*)(x + r0 * 512 + j0);
  float2 x1 = *(const float2*)(x + (r0 + 1) * 512 + j0);
  *(float2*)(dst + r0 * 512 + j0)       = make_float2(x0.x * (ra.x + b20), x0.y * (ra.y + b21));
  *(float2*)(dst + (r0 + 1) * 512 + j0) = make_float2(x1.x * (rb.x + b20), x1.y * (rb.y + b21));
}

// ================= kRead: read matmul + per-tile max/argmax (R0) ===========
__global__ __launch_bounds__(512) void k_read(
    const float* __restrict__ W, const float* __restrict__ brd,
    const float* __restrict__ xr,
    float* __restrict__ pmax, int* __restrict__ pidx) {
  __shared__ __align__(16) float xs[16 * 512];
  int tid = threadIdx.x, lane = tid & 63, w = tid >> 6;
  int i = blockIdx.y, tile = blockIdx.x;
  {
    const float4* s4 = (const float4*)xr;
    float4* d4 = (float4*)xs;
    for (int t = tid; t < 2048; t += 512) d4[t] = s4[t];
  }
  __syncthreads();
  int b0 = w * 2, b1 = b0 + 1;
  int s0 = tile * 128 + lane * 2;
  int sC = (s0 > 9998) ? 9998 : s0;
  const float* Wp = W + i * 10000 + sC;
  const float* xap = xs + b0 * 512;
  const float* xbp = xs + b1 * 512;
  float a00 = 0.f, a01 = 0.f, a10 = 0.f, a11 = 0.f;
#pragma unroll 8
  for (int c = 0; c < 512; c += 4) {
    float4 xa = *(const float4*)(xap + c);
    float4 xb = *(const float4*)(xbp + c);
    float2 w0 = *(const float2*)(Wp + (size_t)(c + 0) * 30000);
    float2 w1 = *(const float2*)(Wp + (size_t)(c + 1) * 30000);
    float2 w2 = *(const float2*)(Wp + (size_t)(c + 2) * 30000);
    float2 w3 = *(const float2*)(Wp + (size_t)(c + 3) * 30000);
    a00 = fmaf(xa.x, w0.x, a00); a01 = fmaf(xa.x, w0.y, a01);
    a10 = fmaf(xb.x, w0.x, a10); a11 = fmaf(xb.x, w0.y, a11);
    a00 = fmaf(xa.y, w1.x, a00); a01 = fmaf(xa.y, w1.y, a01);
    a10 = fmaf(xb.y, w1.x, a10); a11 = fmaf(xb.y, w1.y, a11);
    a00 = fmaf(xa.z, w2.x, a00); a01 = fmaf(xa.z, w2.y, a01);
    a10 = fmaf(xb.z, w2.x, a10); a11 = fmaf(xb.z, w2.y, a11);
    a00 = fmaf(xa.w, w3.x, a00); a01 = fmaf(xa.w, w3.y, a01);
    a10 = fmaf(xb.w, w3.x, a10); a11 = fmaf(xb.w, w3.y, a11);
  }
  float2 bb = *(const float2*)(brd + i * 10000 + sC);
  bool ok0 = (s0 < 10000), ok1 = (s0 + 1 < 10000);
  float v00 = a00 + bb.x, v01 = a01 + bb.y;
  float v10 = a10 + bb.x, v11 = a11 + bb.y;
  float bv0 = ok0 ? v00 : -FLT_MAX; int bi0 = s0;
  if (ok1 && v01 > bv0) { bv0 = v01; bi0 = s0 + 1; }
  float bv1 = ok0 ? v10 : -FLT_MAX; int bi1 = s0;
  if (ok1 && v11 > bv1) { bv1 = v11; bi1 = s0 + 1; }
#pragma unroll
  for (int o = 32; o > 0; o >>= 1) {
    float ov = __shfl_down(bv0, o); int oi = __shfl_down(bi0, o);
    if (ov > bv0) { bv0 = ov; bi0 = oi; }
    ov = __shfl_down(bv1, o); oi = __shfl_down(bi1, o);
    if (ov > bv1) { bv1 = ov; bi1 = oi; }
  }
  if (lane == 0) {
    int base = (i * 16 + b0) * NTILES + tile;
    pmax[base] = bv0; pidx[base] = bi0;
    base = (i * 16 + b1) * NTILES + tile;
    pmax[base] = bv1; pidx[base] = bi1;
  }
}

// ===== kG: argmax finalize + gather XC + UPDW sigmoid. grid 48, 512 thr ====
__global__ __launch_bounds__(512) void k_gather(
    const float* __restrict__ mem, const float* __restrict__ x,
    const float* __restrict__ pmax, const int* __restrict__ pidx,
    const float* __restrict__ XU, const float* __restrict__ Wuw,
    const float* __restrict__ buw,
    float* __restrict__ RDW, float* __restrict__ UPDW, float* __restrict__ XC) {
  __shared__ int sidx;
  __shared__ float red[16];
  int bi = blockIdx.x, b = bi / 3, i = bi % 3;
  int tid = threadIdx.x, lane = tid & 63;
  if (tid < 64) {
    float bv = -FLT_MAX; int bix = 0;
    const float* pm = pmax + (i * 16 + b) * NTILES;
    const int* pi = pidx + (i * 16 + b) * NTILES;
    for (int t = lane; t < NTILES; t += 64) {
      float v = pm[t]; int ix = pi[t];
      if (v > bv || (v == bv && ix < bix)) { bv = v; bix = ix; }
    }
#pragma unroll
    for (int o = 32; o > 0; o >>= 1) {
      float ov = __shfl_down(bv, o); int oi = __shfl_down(bix, o);
      if (ov > bv || (ov == bv && oi < bix)) { bv = ov; bix = oi; }
    }
    if (lane == 0) { sidx = bix; RDW[bi] = tanhf(bv); }
  }
  __syncthreads();
  for (int t = tid; t < 768; t += 512)
    XC[(size_t)bi * 768 + t] = (t < 256)
        ? mem[((size_t)b * 10000 + sidx) * 256 + t]
        : x[b * 512 + (t - 256)];
  // UPDW[b,i] = sigmoid(dot(XU[b,:], Wuw[:,i]) + buw[i])
  float si = block_sum(XU[b * 512 + tid] * Wuw[tid * 3 + i], red);
  if (tid == 0) UPDW[bi] = 1.f / (1.f + expf(-(si + buw[i])));
}

// ================= C1: fa_um mm1 partials. grid (6 jt, 6 ks, 3 g) ==========
__global__ __launch_bounds__(512) void k_mm1_u(
    const float* __restrict__ XC, const float* __restrict__ w1um,
    float* __restrict__ TPU) {
  __shared__ float xs[16 * 128];
  int jt = blockIdx.x, ks = blockIdx.y, g = blockIdx.z, tid = threadIdx.x;
  for (int t = tid; t < 2048; t += 512) {
    int r = t >> 7, kk = t & 127;
    xs[t] = XC[(size_t)(g * 16 + r) * 768 + ks * 128 + kk];
  }
  __syncthreads();
  float2 ra, rb;
  mm_tile16(xs, w1um, 768, ks * 128, jt * 128, ra, rb);
  store_tile16(TPU + (size_t)(ks * 48 + g * 16) * 768, 768, jt * 128, ra, rb);
}

// ====== C2: assemble + softmax + mm2 + xc*(..) -> XU2. grid (6 jt, 3 g) ====
__global__ __launch_bounds__(512) void k_sm2_u(
    const float* __restrict__ TPU, const float* __restrict__ XC,
    const float* __restrict__ b1um, const float* __restrict__ w2um,
    const float* __restrict__ b2um, float* __restrict__ XU2) {
  __shared__ float xs[12288];
  int jt = blockIdx.x, g = blockIdx.y, tid = threadIdx.x;
  int lane = tid & 63, w = tid >> 6;
  for (int e = tid; e < 12288; e += 512) {
    int r = e / 768, j = e - r * 768;
    float v = b1um[j];
#pragma unroll
    for (int ks = 0; ks < 6; ks++) v += TPU[(size_t)(ks * 48 + g * 16 + r) * 768 + j];
    xs[e] = v;
  }
  __syncthreads();
  softmax_rows(xs, 768);
  float2 ra, rb;
  mm_rows(xs, 768, 768, w2um, 768, jt * 128, ra, rb);
  int r0 = w * 2, j0 = jt * 128 + lane * 2, bi0 = g * 16 + r0;
  float b0 = b2um[j0], b1v = b2um[j0 + 1];
  float2 xc0 = *(const float2*)(XC + (size_t)bi0 * 768 + j0);
  float2 xc1 = *(const float2*)(XC + (size_t)(bi0 + 1) * 768 + j0);
  *(float2*)(XU2 + (size_t)bi0 * 768 + j0) =
      make_float2(xc0.x * (ra.x + b0), xc0.y * (ra.y + b1v));
  *(float2*)(XU2 + (size_t)(bi0 + 1) * 768 + j0) =
      make_float2(xc1.x * (rb.x + b0), xc1.y * (rb.y + b1v));
}

// ====== C3: xu2 @ W_um + bias + relu + u-gate -> RNEW. grid 6 ==============
__global__ __launch_bounds__(512) void k_wum(
    const float* __restrict__ XU2, const float* __restrict__ XC,
    const float* __restrict__ Wum, const float* __restrict__ bum,
    const float* __restrict__ UPDW, float* __restrict__ RNEW) {
  __shared__ float xs[12288];
  int bid = blockIdx.x, g = bid >> 1, jt = bid & 1, tid = threadIdx.x;
  int lane = tid & 63, w = tid >> 6;
  const float* src = XU2 + (size_t)(g * 16) * 768;
  for (int e = tid; e < 12288; e += 512) xs[e] = src[e];
  __syncthreads();
  float2 ra, rb;
  mm_rows(xs, 768, 768, Wum, 256, jt * 128, ra, rb);
  int r0 = w * 2, j0 = jt * 128 + lane * 2, bi0 = g * 16 + r0;
  float bb0 = bum[j0], bb1 = bum[j0 + 1];
  float u0 = UPDW[bi0], u1 = UPDW[bi0 + 1];
  float2 xc0 = *(const float2*)(XC + (size_t)bi0 * 768 + j0);
  float2 xc1 = *(const float2*)(XC + (size_t)(bi0 + 1) * 768 + j0);
  *(float2*)(RNEW + (size_t)bi0 * 256 + j0) =
      make_float2(u0 * fmaxf(ra.x + bb0, 0.f) + (1.f - u0) * xc0.x,
                  u0 * fmaxf(ra.y + bb1, 0.f) + (1.f - u0) * xc0.y);
  *(float2*)(RNEW + (size_t)(bi0 + 1) * 256 + j0) =
      make_float2(u1 * fmaxf(rb.x + bb0, 0.f) + (1.f - u1) * xc1.x,
                  u1 * fmaxf(rb.y + bb1, 0.f) + (1.f - u1) * xc1.y);
}

// ================= D1: fa_am mm1 partials. grid (4 jt, 4 ks) ===============
__global__ __launch_bounds__(512) void k_mm1_m(
    const float* __restrict__ RNEW, const float* __restrict__ M,
    const float* __restrict__ w1am, float* __restrict__ TPM, int i) {
  __shared__ float xs[16 * 128];
  int jt = blockIdx.x, ks = blockIdx.y, tid = threadIdx.x;
  for (int t = tid; t < 2048; t += 512) {
    int b = t >> 7, kk = t & 127;
    xs[t] = (ks < 2) ? RNEW[(size_t)(b * 3 + i) * 256 + ks * 128 + kk]
                     : (i == 0 ? 0.f : M[b * 256 + (ks - 2) * 128 + kk]);
  }
  __syncthreads();
  float2 ra, rb;
  mm_tile16(xs, w1am, 512, ks * 128, jt * 128, ra, rb);
  store_tile16(TPM + (size_t)(ks * 16) * 512, 512, jt * 128, ra, rb);
}

// ====== D2: assemble + softmax + mm2 + xc*(..) -> XA. grid 4 ==============
__global__ __launch_bounds__(512) void k_sm2_m(
    const float* __restrict__ TPM, const float* __restrict__ RNEW,
    const float* __restrict__ M, const float* __restrict__ b1am,
    const float* __restrict__ w2am, const float* __restrict__ b2am,
    float* __restrict__ XA, int i) {
  __shared__ float xs[8192];
  int jt = blockIdx.x, tid = threadIdx.x;
  int lane = tid & 63, w = tid >> 6;
  for (int e = tid; e < 8192; e += 512) {
    int b = e >> 9, j = e & 511;
    float v = b1am[j];
#pragma unroll
    for (int ks = 0; ks < 4; ks++) v += TPM[(size_t)(ks * 16 + b) * 512 + j];
    xs[e] = v;
  }
  __syncthreads();
  softmax_rows(xs, 512);
  float2 ra, rb;
  mm_rows(xs, 512, 512, w2am, 512, jt * 128, ra, rb);
  int r0 = w * 2, j0 = jt * 128 + lane * 2;
  float b0 = b2am[j0], b1v = b2am[j0 + 1];
  float2 c0, c1;
  if (j0 < 256) {
    c0 = *(const float2*)(RNEW + (size_t)(r0 * 3 + i) * 256 + j0);
    c1 = *(const float2*)(RNEW + (size_t)((r0 + 1) * 3 + i) * 256 + j0);
  } else if (i == 0) {
    c0 = make_float2(0.f, 0.f);
    c1 = make_float2(0.f, 0.f);
  } else {
    c0 = *(const float2*)(M + r0 * 256 + (j0 - 256));
    c1 = *(const float2*)(M + (r0 + 1) * 256 + (j0 - 256));
  }
  *(float2*)(XA + r0 * 512 + j0) =
      make_float2(c0.x * (ra.x + b0), c0.y * (ra.y + b1v));
  *(float2*)(XA + (r0 + 1) * 512 + j0) =
      make_float2(c1.x * (rb.x + b0), c1.y * (rb.y + b1v));
}

// ====== D3: xa @ W_am + gate -> M (+ tanh out on last). grid 2 ============
__global__ __launch_bounds__(512) void k_wam(
    const float* __restrict__ XA, const float* __restrict__ Wam,
    const float* __restrict__ bam, const float* __restrict__ RDW,
    float* __restrict__ M, float* __restrict__ out, int i, int last) {
  __shared__ float xs[8192];
  int jt = blockIdx.x, tid = threadIdx.x;
  int lane = tid & 63, w = tid >> 6;
  for (int e = tid; e < 8192; e += 512) xs[e] = XA[e];
  __syncthreads();
  float2 ra, rb;
  mm_rows(xs, 512, 512, Wam, 256, jt * 128, ra, rb);
  int r0 = w * 2, j0 = jt * 128 + lane * 2;
  float bb0 = bam[j0], bb1 = bam[j0 + 1];
  float u0 = RDW[r0 * 3 + i], u1 = RDW[(r0 + 1) * 3 + i];
  float m00 = u0 * fmaxf(ra.x + bb0, 0.f), m01 = u0 * fmaxf(ra.y + bb1, 0.f);
  float m10 = u1 * fmaxf(rb.x + bb0, 0.f), m11 = u1 * fmaxf(rb.y + bb1, 0.f);
  *(float2*)(M + r0 * 256 + j0) = make_float2(m00, m01);
  *(float2*)(M + (r0 + 1) * 256 + j0) = make_float2(m10, m11);
  if (last) {
    *(float2*)(out + r0 * 256 + j0) = make_float2(tanhf(m00), tanhf(m01));
    *(float2*)(out + (r0 + 1) * 256 + j0) = make_float2(tanhf(m10), tanhf(m11));
  }
}

// ---------------- launch ----------------
extern "C" void kernel_launch(void* const* d_in, const int* in_sizes, int n_in,
                              void* d_out, int out_size, void* d_ws, size_t ws_size,
                              hipStream_t stream) {
  const float* x    = (const float*)d_in[0];
  const float* mem  = (const float*)d_in[1];
  const float* w1r  = (const float*)d_in[2];
  const float* b1r  = (const float*)d_in[3];
  const float* w2r  = (const float*)d_in[4];
  const float* b2r  = (const float*)d_in[5];
  const float* Wrd  = (const float*)d_in[6];
  const float* brd  = (const float*)d_in[7];
  const float* w1u  = (const float*)d_in[8];
  const float* b1u  = (const float*)d_in[9];
  const float* w2u  = (const float*)d_in[10];
  const float* b2u  = (const float*)d_in[11];
  const float* Wuw  = (const float*)d_in[12];
  const float* buw  = (const float*)d_in[13];
  const float* w1um = (const float*)d_in[14];
  const float* b1um = (const float*)d_in[15];
  const float* w2um = (const float*)d_in[16];
  const float* b2um = (const float*)d_in[17];
  const float* Wum  = (const float*)d_in[18];
  const float* bum  = (const float*)d_in[19];
  const float* w1am = (const float*)d_in[20];
  const float* b1am = (const float*)d_in[21];
  const float* w2am = (const float*)d_in[22];
  const float* b2am = (const float*)d_in[23];
  const float* Wam  = (const float*)d_in[24];
  const float* bam  = (const float*)d_in[25];

  float* ws   = (float*)d_ws;
  float* XR   = ws + WS_XR;
  float* UPDW = ws + WS_UPDW;
  float* RDW  = ws + WS_READW;
  float* PMAX = ws + WS_PMAX;
  int*   PIDX = (int*)(ws + WS_PIDX);
  float* RNEW = ws + WS_RNEW;
  float* M    = ws + WS_M;
  float* XU   = ws + WS_XU;
  float* XA   = ws + WS_XA;
  float* TPA  = ws + WS_TPA;
  float* TPM  = ws + WS_TPM;
  float* XU2  = ws + WS_XU2;
  float* TPU  = ws + WS_TPU;
  float* XC   = ws + WS_XC;
  float* out  = (float*)d_out;

  // Phase A (4 kernels -> 2)
  k_mm1_a<<<dim3(4, 4, 2), 512, 0, stream>>>(x, w1r, w1u, TPA);
  k_sm2_a<<<dim3(4, 2),    512, 0, stream>>>(TPA, x, b1r, b1u, w2r, w2u,
                                             b2r, b2u, XR, XU);
  // Read path
  k_read  <<<dim3(NTILES, 3), 512, 0, stream>>>(Wrd, brd, XR, PMAX, PIDX);
  k_gather<<<48,              512, 0, stream>>>(mem, x, PMAX, PIDX, XU,
                                                Wuw, buw, RDW, UPDW, XC);
  // Phase C (5 kernels -> 3)
  k_mm1_u<<<dim3(6, 6, 3), 512, 0, stream>>>(XC, w1um, TPU);
  k_sm2_u<<<dim3(6, 3),    512, 0, stream>>>(TPU, XC, b1um, w2um, b2um, XU2);
  k_wum  <<<6,             512, 0, stream>>>(XU2, XC, Wum, bum, UPDW, RNEW);
  // Phase D (5 kernels/iter -> 3)
  for (int i = 0; i < 3; i++) {
    k_mm1_m<<<dim3(4, 4), 512, 0, stream>>>(RNEW, M, w1am, TPM, i);
    k_sm2_m<<<4,          512, 0, stream>>>(TPM, RNEW, M, b1am, w2am, b2am, XA, i);
    k_wam  <<<2,          512, 0, stream>>>(XA, Wam, bam, RDW, M, out, i, i == 2);
  }
}

// Round 7
// 502.089 us; speedup vs baseline: 3.7240x; 1.4577x over previous
//
#include <hip/hip_runtime.h>
#include <cfloat>
#include <cmath>

constexpr int NTILES = 79;   // ceil(10000 / 128) for the read matmul

// ---------------- workspace layout (float offsets) ----------------
enum : int {
  WS_XR    = 0,        // 16*512
  WS_XU    = 8192,     // 16*512
  WS_READW = 16384,    // 48
  WS_PMAX  = 16432,    // 3*16*79
  WS_PIDX  = 20224,    // 3*16*79 (ints)
  WS_RNEW  = 24016,    // 48*256
};                     // ~36304 floats (~145 KB)

// ---------------- reductions (wave = 64) ----------------
__device__ __forceinline__ float wave_sum(float v) {
#pragma unroll
  for (int o = 32; o > 0; o >>= 1) v += __shfl_xor(v, o);
  return v;
}
__device__ __forceinline__ float wave_max(float v) {
#pragma unroll
  for (int o = 32; o > 0; o >>= 1) v = fmaxf(v, __shfl_xor(v, o));
  return v;
}
__device__ __forceinline__ float block_sum(float v, float* red) {
  int lane = threadIdx.x & 63, w = threadIdx.x >> 6, nw = blockDim.x >> 6;
  v = wave_sum(v);
  __syncthreads();
  if (lane == 0) red[w] = v;
  __syncthreads();
  float s = 0.f;
  for (int k = 0; k < nw; k++) s += red[k];
  return s;
}
__device__ __forceinline__ float block_max(float v, float* red) {
  int lane = threadIdx.x & 63, w = threadIdx.x >> 6, nw = blockDim.x >> 6;
  v = wave_max(v);
  __syncthreads();
  if (lane == 0) red[w] = v;
  __syncthreads();
  float s = -FLT_MAX;
  for (int k = 0; k < nw; k++) s = fmaxf(s, red[k]);
  return s;
}

// ---------------- wave-split-K row matmul ----------------
// 512 thr = 8 waves. Wave w owns K-slice [w*K/8, (w+1)*K/8); lane owns
// columns {j*64+lane : j<NC/64} -> NC/64 INDEPENDENT accumulator chains,
// coalesced 256B wave loads (k_read's proven ILP pattern).
// Partials land in red[8][NC]; caller __syncthreads then red8-sums.
template<int K, int NC>
__device__ __forceinline__ void mm_ksplit(const float* __restrict__ xl,
                                          const float* __restrict__ W,
                                          float* __restrict__ red) {
  constexpr int KS = K / 8;
  constexpr int J  = NC / 64;
  int lane = threadIdx.x & 63, w = threadIdx.x >> 6;
  const float* Wp = W + (size_t)(w * KS) * NC + lane;
  const float* xp = xl + w * KS;
  float acc[J];
#pragma unroll
  for (int j = 0; j < J; j++) acc[j] = 0.f;
#pragma unroll 4
  for (int k = 0; k < KS; k++) {
    float xk = xp[k];
    const float* Wr = Wp + (size_t)k * NC;
#pragma unroll
    for (int j = 0; j < J; j++) acc[j] = fmaf(xk, Wr[j * 64], acc[j]);
  }
  float* rp = red + w * NC + lane;
#pragma unroll
  for (int j = 0; j < J; j++) rp[j * 64] = acc[j];
}
__device__ __forceinline__ float red8(const float* __restrict__ red, int NC, int t) {
  float s = 0.f;
#pragma unroll
  for (int w = 0; w < 8; w++) s += red[w * NC + t];
  return s;
}

// ============ kA2: full fa_r (m=0) / fa_u (m=1) per row -> XR / XU =========
__global__ __launch_bounds__(512) void kA2(
    const float* __restrict__ x,
    const float* __restrict__ w1r, const float* __restrict__ b1r,
    const float* __restrict__ w2r, const float* __restrict__ b2r,
    const float* __restrict__ w1u, const float* __restrict__ b1u,
    const float* __restrict__ w2u, const float* __restrict__ b2u,
    float* __restrict__ XR, float* __restrict__ XU) {
  __shared__ float xl[512], hl[512], red[8 * 512], red16[16];
  int bid = blockIdx.x, m = bid >> 4, b = bid & 15, tid = threadIdx.x;
  const float* w1 = m ? w1u : w1r;  const float* b1 = m ? b1u : b1r;
  const float* w2 = m ? w2u : w2r;  const float* b2 = m ? b2u : b2r;
  float xv = x[b * 512 + tid];
  xl[tid] = xv;
  __syncthreads();
  mm_ksplit<512, 512>(xl, w1, red);
  __syncthreads();
  float v = red8(red, 512, tid) + b1[tid];
  float mx = block_max(v, red16);
  float e = expf(v - mx);
  float s = block_sum(e, red16);
  hl[tid] = e / s;
  __syncthreads();
  mm_ksplit<512, 512>(hl, w2, red);
  __syncthreads();
  float y = red8(red, 512, tid) + b2[tid];
  (m ? XU : XR)[b * 512 + tid] = xv * y;
}

// ============ k_read: read matmul + per-tile max/argmax (R0-verbatim) ======
__global__ __launch_bounds__(512) void k_read(
    const float* __restrict__ W, const float* __restrict__ brd,
    const float* __restrict__ xr,
    float* __restrict__ pmax, int* __restrict__ pidx) {
  __shared__ __align__(16) float xs[16 * 512];
  int tid = threadIdx.x, lane = tid & 63, w = tid >> 6;
  int i = blockIdx.y, tile = blockIdx.x;
  {
    const float4* s4 = (const float4*)xr;
    float4* d4 = (float4*)xs;
    for (int t = tid; t < 2048; t += 512) d4[t] = s4[t];
  }
  __syncthreads();
  int b0 = w * 2, b1 = b0 + 1;
  int s0 = tile * 128 + lane * 2;
  int sC = (s0 > 9998) ? 9998 : s0;
  const float* Wp = W + i * 10000 + sC;
  const float* xap = xs + b0 * 512;
  const float* xbp = xs + b1 * 512;
  float a00 = 0.f, a01 = 0.f, a10 = 0.f, a11 = 0.f;
#pragma unroll 8
  for (int c = 0; c < 512; c += 4) {
    float4 xa = *(const float4*)(xap + c);
    float4 xb = *(const float4*)(xbp + c);
    float2 w0 = *(const float2*)(Wp + (size_t)(c + 0) * 30000);
    float2 w1 = *(const float2*)(Wp + (size_t)(c + 1) * 30000);
    float2 w2 = *(const float2*)(Wp + (size_t)(c + 2) * 30000);
    float2 w3 = *(const float2*)(Wp + (size_t)(c + 3) * 30000);
    a00 = fmaf(xa.x, w0.x, a00); a01 = fmaf(xa.x, w0.y, a01);
    a10 = fmaf(xb.x, w0.x, a10); a11 = fmaf(xb.x, w0.y, a11);
    a00 = fmaf(xa.y, w1.x, a00); a01 = fmaf(xa.y, w1.y, a01);
    a10 = fmaf(xb.y, w1.x, a10); a11 = fmaf(xb.y, w1.y, a11);
    a00 = fmaf(xa.z, w2.x, a00); a01 = fmaf(xa.z, w2.y, a01);
    a10 = fmaf(xb.z, w2.x, a10); a11 = fmaf(xb.z, w2.y, a11);
    a00 = fmaf(xa.w, w3.x, a00); a01 = fmaf(xa.w, w3.y, a01);
    a10 = fmaf(xb.w, w3.x, a10); a11 = fmaf(xb.w, w3.y, a11);
  }
  float2 bb = *(const float2*)(brd + i * 10000 + sC);
  bool ok0 = (s0 < 10000), ok1 = (s0 + 1 < 10000);
  float v00 = a00 + bb.x, v01 = a01 + bb.y;
  float v10 = a10 + bb.x, v11 = a11 + bb.y;
  float bv0 = ok0 ? v00 : -FLT_MAX; int bi0 = s0;
  if (ok1 && v01 > bv0) { bv0 = v01; bi0 = s0 + 1; }
  float bv1 = ok0 ? v10 : -FLT_MAX; int bi1 = s0;
  if (ok1 && v11 > bv1) { bv1 = v11; bi1 = s0 + 1; }
#pragma unroll
  for (int o = 32; o > 0; o >>= 1) {
    float ov = __shfl_down(bv0, o); int oi = __shfl_down(bi0, o);
    if (ov > bv0) { bv0 = ov; bi0 = oi; }
    ov = __shfl_down(bv1, o); oi = __shfl_down(bi1, o);
    if (ov > bv1) { bv1 = ov; bi1 = oi; }
  }
  if (lane == 0) {
    int base = (i * 16 + b0) * NTILES + tile;
    pmax[base] = bv0; pidx[base] = bi0;
    base = (i * 16 + b1) * NTILES + tile;
    pmax[base] = bv1; pidx[base] = bi1;
  }
}

// ============ kC2: argmax + gather + UPDW + full fa_um + W_um + gate =======
// One block per (b,i). 512 thr; cols 768 -> thread t owns t (and 512+t if t<256).
__global__ __launch_bounds__(512) void kC2(
    const float* __restrict__ mem, const float* __restrict__ x,
    const float* __restrict__ pmax, const int* __restrict__ pidx,
    const float* __restrict__ XU, const float* __restrict__ Wuw,
    const float* __restrict__ buw,
    const float* __restrict__ w1um, const float* __restrict__ b1um,
    const float* __restrict__ w2um, const float* __restrict__ b2um,
    const float* __restrict__ Wum, const float* __restrict__ bum,
    float* __restrict__ RDW, float* __restrict__ RNEW) {
  __shared__ float xcl[768], hl[768], xal[768], red[8 * 768], red16[16];
  __shared__ float s_u;
  __shared__ int sidx;
  int bi = blockIdx.x, b = bi / 3, i = bi % 3;
  int tid = threadIdx.x, lane = tid & 63;
  // argmax finalize over 79 tile-partials (wave 0)
  if (tid < 64) {
    float bv = -FLT_MAX; int bix = 0;
    const float* pm = pmax + (i * 16 + b) * NTILES;
    const int* pi = pidx + (i * 16 + b) * NTILES;
    for (int t = lane; t < NTILES; t += 64) {
      float v = pm[t]; int ix = pi[t];
      if (v > bv || (v == bv && ix < bix)) { bv = v; bix = ix; }
    }
#pragma unroll
    for (int o = 32; o > 0; o >>= 1) {
      float ov = __shfl_down(bv, o); int oi = __shfl_down(bix, o);
      if (ov > bv || (ov == bv && oi < bix)) { bv = ov; bix = oi; }
    }
    if (lane == 0) { sidx = bix; RDW[bi] = tanhf(bv); }
  }
  // UPDW (kept local): sigmoid(dot(XU[b,:], Wuw[:,i]) + buw[i])
  float du = XU[b * 512 + tid] * Wuw[tid * 3 + i];
  float su = block_sum(du, red16);
  if (tid == 0) s_u = 1.f / (1.f + expf(-(su + buw[i])));
  __syncthreads();
  // gather xc = [mem_row(256), x(512)]
  for (int t = tid; t < 768; t += 512)
    xcl[t] = (t < 256) ? mem[((size_t)b * 10000 + sidx) * 256 + t]
                       : x[b * 512 + t - 256];
  __syncthreads();
  // mm1 (768x768)
  mm_ksplit<768, 768>(xcl, w1um, red);
  __syncthreads();
  float v0 = red8(red, 768, tid) + b1um[tid];
  float v1 = (tid < 256) ? red8(red, 768, 512 + tid) + b1um[512 + tid] : -FLT_MAX;
  float mx = block_max(fmaxf(v0, v1), red16);
  float e0 = expf(v0 - mx);
  float e1 = (tid < 256) ? expf(v1 - mx) : 0.f;
  float s = block_sum(e0 + e1, red16);
  float inv = 1.f / s;
  hl[tid] = e0 * inv;
  if (tid < 256) hl[512 + tid] = e1 * inv;
  __syncthreads();
  // mm2 (768x768) + elementwise
  mm_ksplit<768, 768>(hl, w2um, red);
  __syncthreads();
  xal[tid] = xcl[tid] * (red8(red, 768, tid) + b2um[tid]);
  if (tid < 256)
    xal[512 + tid] = xcl[512 + tid] * (red8(red, 768, 512 + tid) + b2um[512 + tid]);
  __syncthreads();
  // W_um (768x256) + relu + u-gate -> RNEW
  mm_ksplit<768, 256>(xal, Wum, red);
  __syncthreads();
  if (tid < 256) {
    float sf = red8(red, 256, tid) + bum[tid];
    float u = s_u;
    RNEW[(size_t)bi * 256 + tid] = u * fmaxf(sf, 0.f) + (1.f - u) * xcl[tid];
  }
}

// ============ kD2: all 3 fa_am iterations, M kept in LDS ==================
// One block per batch row b.
__global__ __launch_bounds__(512) void kD2(
    const float* __restrict__ RNEW,
    const float* __restrict__ w1am, const float* __restrict__ b1am,
    const float* __restrict__ w2am, const float* __restrict__ b2am,
    const float* __restrict__ Wam, const float* __restrict__ bam,
    const float* __restrict__ RDW, float* __restrict__ out) {
  __shared__ float xcl[512], hl[512], xal[512], ml[256], red[8 * 512], red16[16];
  int b = blockIdx.x, tid = threadIdx.x;
  for (int i = 0; i < 3; i++) {
    float xv = (tid < 256) ? RNEW[(size_t)(b * 3 + i) * 256 + tid]
                           : (i == 0 ? 0.f : ml[tid - 256]);
    xcl[tid] = xv;
    __syncthreads();
    mm_ksplit<512, 512>(xcl, w1am, red);
    __syncthreads();
    float v = red8(red, 512, tid) + b1am[tid];
    float mx = block_max(v, red16);
    float e = expf(v - mx);
    float s = block_sum(e, red16);
    hl[tid] = e / s;
    __syncthreads();
    mm_ksplit<512, 512>(hl, w2am, red);
    __syncthreads();
    xal[tid] = xv * (red8(red, 512, tid) + b2am[tid]);
    __syncthreads();
    mm_ksplit<512, 256>(xal, Wam, red);
    __syncthreads();
    if (tid < 256) {
      float mv = RDW[b * 3 + i] * fmaxf(red8(red, 256, tid) + bam[tid], 0.f);
      ml[tid] = mv;
      if (i == 2) out[b * 256 + tid] = tanhf(mv);
    }
    __syncthreads();   // ml visible before next iteration reads it
  }
}

// ---------------- launch ----------------
extern "C" void kernel_launch(void* const* d_in, const int* in_sizes, int n_in,
                              void* d_out, int out_size, void* d_ws, size_t ws_size,
                              hipStream_t stream) {
  const float* x    = (const float*)d_in[0];
  const float* mem  = (const float*)d_in[1];
  const float* w1r  = (const float*)d_in[2];
  const float* b1r  = (const float*)d_in[3];
  const float* w2r  = (const float*)d_in[4];
  const float* b2r  = (const float*)d_in[5];
  const float* Wrd  = (const float*)d_in[6];
  const float* brd  = (const float*)d_in[7];
  const float* w1u  = (const float*)d_in[8];
  const float* b1u  = (const float*)d_in[9];
  const float* w2u  = (const float*)d_in[10];
  const float* b2u  = (const float*)d_in[11];
  const float* Wuw  = (const float*)d_in[12];
  const float* buw  = (const float*)d_in[13];
  const float* w1um = (const float*)d_in[14];
  const float* b1um = (const float*)d_in[15];
  const float* w2um = (const float*)d_in[16];
  const float* b2um = (const float*)d_in[17];
  const float* Wum  = (const float*)d_in[18];
  const float* bum  = (const float*)d_in[19];
  const float* w1am = (const float*)d_in[20];
  const float* b1am = (const float*)d_in[21];
  const float* w2am = (const float*)d_in[22];
  const float* b2am = (const float*)d_in[23];
  const float* Wam  = (const float*)d_in[24];
  const float* bam  = (const float*)d_in[25];

  float* ws   = (float*)d_ws;
  float* XR   = ws + WS_XR;
  float* XU   = ws + WS_XU;
  float* RDW  = ws + WS_READW;
  float* PMAX = ws + WS_PMAX;
  int*   PIDX = (int*)(ws + WS_PIDX);
  float* RNEW = ws + WS_RNEW;
  float* out  = (float*)d_out;

  kA2   <<<32,              512, 0, stream>>>(x, w1r, b1r, w2r, b2r,
                                              w1u, b1u, w2u, b2u, XR, XU);
  k_read<<<dim3(NTILES, 3), 512, 0, stream>>>(Wrd, brd, XR, PMAX, PIDX);
  kC2   <<<48,              512, 0, stream>>>(mem, x, PMAX, PIDX, XU, Wuw, buw,
                                              w1um, b1um, w2um, b2um, Wum, bum,
                                              RDW, RNEW);
  kD2   <<<16,              512, 0, stream>>>(RNEW, w1am, b1am, w2am, b2am,
                                              Wam, bam, RDW, out);
}